// Round 2
// baseline (1015.437 us; speedup 1.0000x reference)
//
#include <hip/hip_runtime.h>
#include <hip/hip_bf16.h>
#include <math.h>

#define BATCH 2
#define C 192
#define H 128
#define W 256
#define HEADS 6
#define HD 32
#define HW (H * W)      // 32768
#define C3 (3 * C)      // 576

struct __align__(8) bf16x4 { __hip_bfloat16 x, y, z, w; };

static __device__ __forceinline__ float bf2f(__hip_bfloat16 v) {
    return __bfloat162float(v);
}

// ---------------------------------------------------------------------------
// conv1x1: out[b, o, p] = sum_c w[o, c] * in[b, c, p], Cin = C = 192 always.
// grid: (HW/1024, Cout/16, BATCH), block 256.
// Each thread: 4 consecutive pixels x 16 consecutive Cout.
// MODE 0: plain   1: silu(out)   2: out * gate
// TOUT: float or __hip_bfloat16
// ---------------------------------------------------------------------------
template <int MODE, typename TOUT>
__global__ __launch_bounds__(256) void conv1x1_kernel(
    const float* __restrict__ in, const float* __restrict__ w,
    TOUT* __restrict__ out, const float* __restrict__ gate)
{
    const int b  = blockIdx.z;
    const int o0 = blockIdx.y * 16;
    const int p  = blockIdx.x * 1024 + threadIdx.x * 4;

    const float* inb = in + (size_t)b * C * HW + p;

    float4 acc[16];
#pragma unroll
    for (int o = 0; o < 16; ++o) acc[o] = make_float4(0.f, 0.f, 0.f, 0.f);

    for (int c = 0; c < C; ++c) {
        const float4 xv = *(const float4*)(inb + (size_t)c * HW);
#pragma unroll
        for (int o = 0; o < 16; ++o) {
            const float wv = w[(size_t)(o0 + o) * C + c];  // wave-uniform -> s_load
            acc[o].x += wv * xv.x;
            acc[o].y += wv * xv.y;
            acc[o].z += wv * xv.z;
            acc[o].w += wv * xv.w;
        }
    }

    if (MODE == 1) {
#pragma unroll
        for (int o = 0; o < 16; ++o) {
            float4 v = acc[o];
            v.x = v.x / (1.f + __expf(-v.x));
            v.y = v.y / (1.f + __expf(-v.y));
            v.z = v.z / (1.f + __expf(-v.z));
            v.w = v.w / (1.f + __expf(-v.w));
            acc[o] = v;
        }
    } else if (MODE == 2) {
#pragma unroll
        for (int o = 0; o < 16; ++o) {
            const float4 g = *(const float4*)(gate + (size_t)b * C * HW +
                                              (size_t)(o0 + o) * HW + p);
            acc[o].x *= g.x;
            acc[o].y *= g.y;
            acc[o].z *= g.z;
            acc[o].w *= g.w;
        }
    }

    TOUT* ob = out + (size_t)b * gridDim.y * 16 * HW + p;
#pragma unroll
    for (int o = 0; o < 16; ++o) {
        TOUT* dst = ob + (size_t)(o0 + o) * HW;
        if constexpr (sizeof(TOUT) == 4) {
            *(float4*)dst = acc[o];
        } else {
            bf16x4 v;
            v.x = __float2bfloat16(acc[o].x);
            v.y = __float2bfloat16(acc[o].y);
            v.z = __float2bfloat16(acc[o].z);
            v.w = __float2bfloat16(acc[o].w);
            *(bf16x4*)dst = v;
        }
    }
}

// ---------------------------------------------------------------------------
// depthwise 3x3, SAME zero padding, bf16 in/out. One thread per element.
// ---------------------------------------------------------------------------
__global__ __launch_bounds__(256) void dwconv3x3_kernel(
    const __hip_bfloat16* __restrict__ t, const float* __restrict__ wd,
    __hip_bfloat16* __restrict__ out)
{
    const int idx = blockIdx.x * 256 + threadIdx.x;   // [0, BATCH*C3*HW)
    const int x  = idx & (W - 1);
    const int y  = (idx >> 8) & (H - 1);
    const int ch = (idx >> 15) % C3;
    const int b  = idx / (C3 * HW);

    const __hip_bfloat16* tp = t + ((size_t)b * C3 + ch) * HW;
    const float* wp = wd + ch * 9;                    // wave-uniform

    float acc = 0.f;
#pragma unroll
    for (int dy = -1; dy <= 1; ++dy) {
        const int yy = y + dy;
        if (yy < 0 || yy >= H) continue;
#pragma unroll
        for (int dx = -1; dx <= 1; ++dx) {
            const int xx = x + dx;
            if (xx < 0 || xx >= W) continue;
            acc += bf2f(tp[yy * W + xx]) * wp[(dy + 1) * 3 + (dx + 1)];
        }
    }
    out[idx] = __float2bfloat16(acc);
}

// ---------------------------------------------------------------------------
// attention: one block per (b, row y, head). 256 threads = 256 query positions.
// K fully staged in LDS (stride 36 floats, 16B-aligned float4 rows, broadcast
// j-loop reads). V staged in 4 tiles of 64 rows inside pass 2.
// LDS: 36864 + 9216 + 2044 = 48.1 KB (< 64 KB limit).
// ---------------------------------------------------------------------------
__global__ __launch_bounds__(256) void attention_kernel(
    const __hip_bfloat16* __restrict__ qkv, const float* __restrict__ rpb,
    float* __restrict__ out)
{
    const int y    = blockIdx.x;
    const int head = blockIdx.y;
    const int b    = blockIdx.z;
    const int t    = threadIdx.x;   // query position i

    __shared__ __align__(16) float Ks[256 * 36];
    __shared__ __align__(16) float Vs[64 * 36];
    __shared__ float rb[511];

    const __hip_bfloat16* qp = qkv + (size_t)b * C3 * HW +
                               (size_t)(head * HD) * HW + (size_t)y * W;
    const __hip_bfloat16* kp = qp + (size_t)C * HW;
    const __hip_bfloat16* vp = kp + (size_t)C * HW;

    // stage K (coalesced: consecutive t -> consecutive addresses)
#pragma unroll
    for (int cc = 0; cc < HD; ++cc) {
        Ks[t * 36 + cc] = bf2f(kp[(size_t)cc * HW + t]);
    }
    // per-head bias row
    rb[t] = rpb[t * HEADS + head];
    if (t < 255) rb[256 + t] = rpb[(256 + t) * HEADS + head];

    const float scale = 0.17677669529663687f;  // 32^-0.5
    float q[HD];
#pragma unroll
    for (int cc = 0; cc < HD; ++cc) q[cc] = bf2f(qp[(size_t)cc * HW + t]) * scale;

    __syncthreads();

    // pass 1: row max
    float m = -1e30f;
    for (int j = 0; j < W; ++j) {
        const float4* kj = (const float4*)&Ks[j * 36];
        float s = 0.f;
#pragma unroll
        for (int r = 0; r < 8; ++r) {
            const float4 kv = kj[r];
            s += q[4 * r + 0] * kv.x + q[4 * r + 1] * kv.y +
                 q[4 * r + 2] * kv.z + q[4 * r + 3] * kv.w;
        }
        s += rb[t - j + 255];
        m = fmaxf(m, s);
    }

    // pass 2: exp-sum + PV accumulate, V staged in 4 tiles of 64 rows
    float l = 0.f;
    float acc[HD];
#pragma unroll
    for (int cc = 0; cc < HD; ++cc) acc[cc] = 0.f;

    for (int tile = 0; tile < 4; ++tile) {
        __syncthreads();   // protect Vs from previous tile's readers
        {
            const int jj = t & 63;
            const int cb = (t >> 6) * 8;
#pragma unroll
            for (int r = 0; r < 8; ++r) {
                Vs[jj * 36 + cb + r] =
                    bf2f(vp[(size_t)(cb + r) * HW + tile * 64 + jj]);
            }
        }
        __syncthreads();

        for (int jj = 0; jj < 64; ++jj) {
            const int j = tile * 64 + jj;
            const float4* kj = (const float4*)&Ks[j * 36];
            float s = 0.f;
#pragma unroll
            for (int r = 0; r < 8; ++r) {
                const float4 kv = kj[r];
                s += q[4 * r + 0] * kv.x + q[4 * r + 1] * kv.y +
                     q[4 * r + 2] * kv.z + q[4 * r + 3] * kv.w;
            }
            s += rb[t - j + 255];
            const float pj = __expf(s - m);
            l += pj;
            const float4* vj = (const float4*)&Vs[jj * 36];
#pragma unroll
            for (int r = 0; r < 8; ++r) {
                const float4 vv = vj[r];
                acc[4 * r + 0] += pj * vv.x;
                acc[4 * r + 1] += pj * vv.y;
                acc[4 * r + 2] += pj * vv.z;
                acc[4 * r + 3] += pj * vv.w;
            }
        }
    }

    const float inv = 1.f / l;
    float* op = out + (size_t)b * C * HW + (size_t)(head * HD) * HW + (size_t)y * W;
#pragma unroll
    for (int cc = 0; cc < HD; ++cc) op[(size_t)cc * HW + t] = acc[cc] * inv;
}

// ---------------------------------------------------------------------------
extern "C" void kernel_launch(void* const* d_in, const int* in_sizes, int n_in,
                              void* d_out, int out_size, void* d_ws, size_t ws_size,
                              hipStream_t stream)
{
    const float* x       = (const float*)d_in[0];
    const float* rpb     = (const float*)d_in[1];
    const float* w_qkv   = (const float*)d_in[2];
    const float* w_depth = (const float*)d_in[3];
    const float* w_pre   = (const float*)d_in[4];
    const float* w_out   = (const float*)d_in[5];
    const float* w_gate  = (const float*)d_in[6];
    float* out = (float*)d_out;

    // workspace layout (201.3 MB total):
    //   [0,            75497472)  t    bf16  [B,3C,H,W]   -> later att f32 (50.3MB)
    //   [75497472,    150994944)  qkv  bf16  [B,3C,H,W]   -> later y   f32 (50.3MB)
    //   [150994944,   201326592)  gate f32   [B,C,H,W]
    char* wsb = (char*)d_ws;
    __hip_bfloat16* buf_t   = (__hip_bfloat16*)wsb;
    __hip_bfloat16* buf_qkv = (__hip_bfloat16*)(wsb + 75497472u);
    float*          buf_gate = (float*)(wsb + 150994944u);
    float*          buf_att  = (float*)wsb;              // alias: t dead after dw
    float*          buf_y    = (float*)(wsb + 75497472u); // alias: qkv dead after attn

    dim3 blk(256);
    dim3 g192(HW / 1024, C / 16, BATCH);   // (32, 12, 2)
    dim3 g576(HW / 1024, C3 / 16, BATCH);  // (32, 36, 2)

    // 1. gate = silu(conv1x1(x, w_gate))           f32 -> f32
    conv1x1_kernel<1, float><<<g192, blk, 0, stream>>>(x, w_gate, buf_gate, nullptr);
    // 2. t = conv1x1(x, w_qkv)                     f32 -> bf16
    conv1x1_kernel<0, __hip_bfloat16><<<g576, blk, 0, stream>>>(x, w_qkv, buf_t, nullptr);
    // 3. qkv = depthwise3x3(t)                     bf16 -> bf16
    dwconv3x3_kernel<<<dim3((BATCH * C3 * HW) / 256), blk, 0, stream>>>(buf_t, w_depth, buf_qkv);
    // 4. att = attention(qkv, rpb)                 bf16 -> f32
    attention_kernel<<<dim3(H, HEADS, BATCH), blk, 0, stream>>>(buf_qkv, rpb, buf_att);
    // 5. y = conv1x1(att, w_pre) * gate            f32 -> f32
    conv1x1_kernel<2, float><<<g192, blk, 0, stream>>>(buf_att, w_pre, buf_y, buf_gate);
    // 6. out = conv1x1(y, w_out)                   f32 -> f32
    conv1x1_kernel<0, float><<<g192, blk, 0, stream>>>(buf_y, w_out, out, nullptr);
}

// Round 3
// 700.970 us; speedup vs baseline: 1.4486x; 1.4486x over previous
//
#include <hip/hip_runtime.h>
#include <hip/hip_bf16.h>
#include <math.h>

#define BATCH 2
#define C 192
#define H 128
#define W 256
#define HEADS 6
#define HD 32
#define HW (H * W)      // 32768
#define C3 (3 * C)      // 576

typedef unsigned short ushort_t;
using bf16x8 = __attribute__((ext_vector_type(8))) short;
using f32x4  = __attribute__((ext_vector_type(4))) float;

struct __align__(8) bf16x4 { __hip_bfloat16 x, y, z, w; };

static __device__ __forceinline__ float bf2f(__hip_bfloat16 v) {
    return __bfloat162float(v);
}
static __device__ __forceinline__ ushort_t f2bfbits(float f) {
    __hip_bfloat16 h = __float2bfloat16(f);
    return *reinterpret_cast<ushort_t*>(&h);
}

// ---------------------------------------------------------------------------
// conv1x1 (unchanged from R2): out[b,o,p] = sum_c w[o,c] in[b,c,p]
// ---------------------------------------------------------------------------
template <int MODE, typename TOUT>
__global__ __launch_bounds__(256) void conv1x1_kernel(
    const float* __restrict__ in, const float* __restrict__ w,
    TOUT* __restrict__ out, const float* __restrict__ gate)
{
    const int b  = blockIdx.z;
    const int o0 = blockIdx.y * 16;
    const int p  = blockIdx.x * 1024 + threadIdx.x * 4;

    const float* inb = in + (size_t)b * C * HW + p;

    float4 acc[16];
#pragma unroll
    for (int o = 0; o < 16; ++o) acc[o] = make_float4(0.f, 0.f, 0.f, 0.f);

    for (int c = 0; c < C; ++c) {
        const float4 xv = *(const float4*)(inb + (size_t)c * HW);
#pragma unroll
        for (int o = 0; o < 16; ++o) {
            const float wv = w[(size_t)(o0 + o) * C + c];
            acc[o].x += wv * xv.x;
            acc[o].y += wv * xv.y;
            acc[o].z += wv * xv.z;
            acc[o].w += wv * xv.w;
        }
    }

    if (MODE == 1) {
#pragma unroll
        for (int o = 0; o < 16; ++o) {
            float4 v = acc[o];
            v.x = v.x / (1.f + __expf(-v.x));
            v.y = v.y / (1.f + __expf(-v.y));
            v.z = v.z / (1.f + __expf(-v.z));
            v.w = v.w / (1.f + __expf(-v.w));
            acc[o] = v;
        }
    } else if (MODE == 2) {
#pragma unroll
        for (int o = 0; o < 16; ++o) {
            const float4 g = *(const float4*)(gate + (size_t)b * C * HW +
                                              (size_t)(o0 + o) * HW + p);
            acc[o].x *= g.x;
            acc[o].y *= g.y;
            acc[o].z *= g.z;
            acc[o].w *= g.w;
        }
    }

    TOUT* ob = out + (size_t)b * gridDim.y * 16 * HW + p;
#pragma unroll
    for (int o = 0; o < 16; ++o) {
        TOUT* dst = ob + (size_t)(o0 + o) * HW;
        if constexpr (sizeof(TOUT) == 4) {
            *(float4*)dst = acc[o];
        } else {
            bf16x4 v;
            v.x = __float2bfloat16(acc[o].x);
            v.y = __float2bfloat16(acc[o].y);
            v.z = __float2bfloat16(acc[o].z);
            v.w = __float2bfloat16(acc[o].w);
            *(bf16x4*)dst = v;
        }
    }
}

// ---------------------------------------------------------------------------
// depthwise 3x3 (unchanged from R2)
// ---------------------------------------------------------------------------
__global__ __launch_bounds__(256) void dwconv3x3_kernel(
    const __hip_bfloat16* __restrict__ t, const float* __restrict__ wd,
    __hip_bfloat16* __restrict__ out)
{
    const int idx = blockIdx.x * 256 + threadIdx.x;
    const int x  = idx & (W - 1);
    const int y  = (idx >> 8) & (H - 1);
    const int ch = (idx >> 15) % C3;
    const int b  = idx / (C3 * HW);

    const __hip_bfloat16* tp = t + ((size_t)b * C3 + ch) * HW;
    const float* wp = wd + ch * 9;

    float acc = 0.f;
#pragma unroll
    for (int dy = -1; dy <= 1; ++dy) {
        const int yy = y + dy;
        if (yy < 0 || yy >= H) continue;
#pragma unroll
        for (int dx = -1; dx <= 1; ++dx) {
            const int xx = x + dx;
            if (xx < 0 || xx >= W) continue;
            acc += bf2f(tp[yy * W + xx]) * wp[(dy + 1) * 3 + (dx + 1)];
        }
    }
    out[idx] = __float2bfloat16(acc);
}

// ---------------------------------------------------------------------------
// MFMA attention. One block (4 waves) per (b, y, head); 1536 blocks.
// Wave wv owns query rows [wv*64, wv*64+64).
//   S = Q K^T via mfma_f32_16x16x32_bf16 (K-dim = 32 channels, 1 mfma/tile)
//   two-pass softmax (pass1 row-max, pass2 recompute S -> P -> PV mfma)
//   P: C-layout -> bf16 -> per-wave LDS buffer -> A-layout frags (m120 pattern)
// LDS map (bytes):
//   [0,     20480)  Ks  [256][40] bf16   (80B row: 16B-aligned frags, 2-way banks)
//   [20480, 37376)  Vt  [32][264] bf16   (V transposed for B-frag contiguity)
//   [37376, 57856)  Qs  [256][40] bf16 -> after frag load: Pbuf, 4 x [64][40]
//   [57856, 61952)  rb4 [4][512]  bf16   (shift-staggered bias copies -> b64 loads)
//   epilogue reuse [0, 32896): Ol [32][257] f32 (coalesced store staging)
// ---------------------------------------------------------------------------
__global__ __launch_bounds__(256) void attention_mfma_kernel(
    const ushort_t* __restrict__ qkv, const float* __restrict__ rpb,
    float* __restrict__ out)
{
    const int y    = blockIdx.x;
    const int head = blockIdx.y;
    const int b    = blockIdx.z;
    const int t    = threadIdx.x;
    const int wv   = t >> 6;
    const int lane = t & 63;
    const int quad = lane >> 4;
    const int l16  = lane & 15;

    __shared__ __align__(16) char smem[61952];
    ushort_t* Ks  = (ushort_t*)smem;              // [256][40]
    ushort_t* Vt  = (ushort_t*)(smem + 20480);    // [32][264]
    ushort_t* Qs  = (ushort_t*)(smem + 37376);    // [256][40] -> Pbuf
    ushort_t* rb4 = (ushort_t*)(smem + 57856);    // [4][512]
    float*    Ol  = (float*)smem;                 // [32][257]

    const ushort_t* qp = qkv + (size_t)b * C3 * HW +
                         (size_t)(head * HD) * HW + (size_t)y * W;
    const ushort_t* kp = qp + (size_t)C * HW;
    const ushort_t* vp = kp + (size_t)C * HW;

    // ---- stage Q, K, V (coalesced global reads; raw bf16 bit copies) ----
#pragma unroll
    for (int c = 0; c < HD; ++c) {
        const ushort_t kv = kp[(size_t)c * HW + t];
        const ushort_t qv = qp[(size_t)c * HW + t];
        const ushort_t vv = vp[(size_t)c * HW + t];
        Ks[t * 40 + c]  = kv;
        Qs[t * 40 + c]  = qv;
        Vt[c * 264 + t] = vv;
    }
    // rb4[s][k] = bf16(rpb[k+s]); aligned-b64 trick: a lane needing
    // rb[base..base+3] loads rb4[base&3][base - (base&3) .. +3].
#pragma unroll
    for (int s = 0; s < 4; ++s) {
        const int k1 = t, k2 = 256 + t;
        const float v1 = (k1 + s < 511) ? rpb[(k1 + s) * HEADS + head] : 0.f;
        const float v2 = (k2 + s < 511) ? rpb[(k2 + s) * HEADS + head] : 0.f;
        rb4[s * 512 + k1] = f2bfbits(v1);
        rb4[s * 512 + k2] = f2bfbits(v2);
    }
    __syncthreads();

    // ---- A-fragments of Q (persist all kernel) ----
    bf16x8 aQ[4];
#pragma unroll
    for (int rt = 0; rt < 4; ++rt) {
        const int row = wv * 64 + rt * 16 + l16;
        aQ[rt] = *(const bf16x8*)&Qs[row * 40 + quad * 8];
    }

    const float scale = 0.17677669529663687f;  // 32^-0.5

    // ---- pass 1: row max of (s*scale + bias) ----
    float m_acc[16];
#pragma unroll
    for (int i = 0; i < 16; ++i) m_acc[i] = -1e30f;

    for (int n = 0; n < 16; ++n) {
        const bf16x8 bK = *(const bf16x8*)&Ks[(n * 16 + l16) * 40 + quad * 8];
#pragma unroll
        for (int rt = 0; rt < 4; ++rt) {
            f32x4 s = {0.f, 0.f, 0.f, 0.f};
            s = __builtin_amdgcn_mfma_f32_16x16x32_bf16(aQ[rt], bK, s, 0, 0, 0);
            const int base = wv * 64 + rt * 16 + quad * 4 - (n * 16 + l16) + 255;
            const int r0 = base & 3;
            const uint2 raw = *(const uint2*)(rb4 + r0 * 512 + (base - r0));
            const float b0 = __uint_as_float(raw.x << 16);
            const float b1 = __uint_as_float(raw.x & 0xffff0000u);
            const float b2 = __uint_as_float(raw.y << 16);
            const float b3 = __uint_as_float(raw.y & 0xffff0000u);
            m_acc[rt * 4 + 0] = fmaxf(m_acc[rt * 4 + 0], s[0] * scale + b0);
            m_acc[rt * 4 + 1] = fmaxf(m_acc[rt * 4 + 1], s[1] * scale + b1);
            m_acc[rt * 4 + 2] = fmaxf(m_acc[rt * 4 + 2], s[2] * scale + b2);
            m_acc[rt * 4 + 3] = fmaxf(m_acc[rt * 4 + 3], s[3] * scale + b3);
        }
    }
    // butterfly max over the 16 lanes of each quad (cols) -> true row max
#pragma unroll
    for (int i = 0; i < 16; ++i) {
        float v = m_acc[i];
        v = fmaxf(v, __shfl_xor(v, 1));
        v = fmaxf(v, __shfl_xor(v, 2));
        v = fmaxf(v, __shfl_xor(v, 4));
        v = fmaxf(v, __shfl_xor(v, 8));
        m_acc[i] = v;
    }

    __syncthreads();   // all waves are done reading Qs -> safe to reuse as Pbuf
    ushort_t* Pb = Qs + wv * 2560;   // per-wave [64][40] bf16

    // ---- pass 2: recompute S, exp, P->LDS, PV mfma ----
    float l_acc[16];
#pragma unroll
    for (int i = 0; i < 16; ++i) l_acc[i] = 0.f;
    f32x4 o_acc[4][2];
#pragma unroll
    for (int rt = 0; rt < 4; ++rt)
#pragma unroll
        for (int ct = 0; ct < 2; ++ct)
            o_acc[rt][ct] = f32x4{0.f, 0.f, 0.f, 0.f};

    for (int c2 = 0; c2 < 8; ++c2) {       // 32 key-columns per step
#pragma unroll
        for (int half = 0; half < 2; ++half) {
            const int n = c2 * 2 + half;
            const bf16x8 bK = *(const bf16x8*)&Ks[(n * 16 + l16) * 40 + quad * 8];
#pragma unroll
            for (int rt = 0; rt < 4; ++rt) {
                f32x4 s = {0.f, 0.f, 0.f, 0.f};
                s = __builtin_amdgcn_mfma_f32_16x16x32_bf16(aQ[rt], bK, s, 0, 0, 0);
                const int base = wv * 64 + rt * 16 + quad * 4 - (n * 16 + l16) + 255;
                const int r0 = base & 3;
                const uint2 raw = *(const uint2*)(rb4 + r0 * 512 + (base - r0));
                const float bia[4] = {
                    __uint_as_float(raw.x << 16),
                    __uint_as_float(raw.x & 0xffff0000u),
                    __uint_as_float(raw.y << 16),
                    __uint_as_float(raw.y & 0xffff0000u)};
#pragma unroll
                for (int reg = 0; reg < 4; ++reg) {
                    const float p = __expf(s[reg] * scale + bia[reg] -
                                           m_acc[rt * 4 + reg]);
                    l_acc[rt * 4 + reg] += p;
                    Pb[(rt * 16 + quad * 4 + reg) * 40 + half * 16 + l16] =
                        f2bfbits(p);
                }
            }
        }
        // PV over this 32-column chunk (intra-wave LDS RAW: compiler lgkmcnt)
#pragma unroll
        for (int rt = 0; rt < 4; ++rt) {
            const bf16x8 aP = *(const bf16x8*)&Pb[(rt * 16 + l16) * 40 + quad * 8];
#pragma unroll
            for (int ct = 0; ct < 2; ++ct) {
                const bf16x8 bV = *(const bf16x8*)
                    &Vt[(ct * 16 + l16) * 264 + c2 * 32 + quad * 8];
                o_acc[rt][ct] = __builtin_amdgcn_mfma_f32_16x16x32_bf16(
                    aP, bV, o_acc[rt][ct], 0, 0, 0);
            }
        }
    }

    // ---- l reduce (butterfly sum over quad lanes) ----
#pragma unroll
    for (int i = 0; i < 16; ++i) {
        float v = l_acc[i];
        v += __shfl_xor(v, 1);
        v += __shfl_xor(v, 2);
        v += __shfl_xor(v, 4);
        v += __shfl_xor(v, 8);
        l_acc[i] = 1.f / v;
    }

    __syncthreads();   // everyone done with Ks/Vt -> reuse as Ol
#pragma unroll
    for (int rt = 0; rt < 4; ++rt) {
        const int i = wv * 64 + rt * 16 + quad * 4;
#pragma unroll
        for (int ct = 0; ct < 2; ++ct) {
            const int c = ct * 16 + l16;
#pragma unroll
            for (int reg = 0; reg < 4; ++reg)
                Ol[c * 257 + i + reg] = o_acc[rt][ct][reg] * l_acc[rt * 4 + reg];
        }
    }
    __syncthreads();

    float* op = out + (size_t)b * C * HW + (size_t)(head * HD) * HW + (size_t)y * W;
#pragma unroll
    for (int c = 0; c < HD; ++c)
        op[(size_t)c * HW + t] = Ol[c * 257 + t];
}

// ---------------------------------------------------------------------------
extern "C" void kernel_launch(void* const* d_in, const int* in_sizes, int n_in,
                              void* d_out, int out_size, void* d_ws, size_t ws_size,
                              hipStream_t stream)
{
    const float* x       = (const float*)d_in[0];
    const float* rpb     = (const float*)d_in[1];
    const float* w_qkv   = (const float*)d_in[2];
    const float* w_depth = (const float*)d_in[3];
    const float* w_pre   = (const float*)d_in[4];
    const float* w_out   = (const float*)d_in[5];
    const float* w_gate  = (const float*)d_in[6];
    float* out = (float*)d_out;

    // workspace (201.3 MB):
    //   [0,            75497472)  t    bf16 [B,3C,H,W]  -> later att f32
    //   [75497472,    150994944)  qkv  bf16 [B,3C,H,W]  -> later y   f32
    //   [150994944,   201326592)  gate f32  [B,C,H,W]
    char* wsb = (char*)d_ws;
    __hip_bfloat16* buf_t    = (__hip_bfloat16*)wsb;
    __hip_bfloat16* buf_qkv  = (__hip_bfloat16*)(wsb + 75497472u);
    float*          buf_gate = (float*)(wsb + 150994944u);
    float*          buf_att  = (float*)wsb;
    float*          buf_y    = (float*)(wsb + 75497472u);

    dim3 blk(256);
    dim3 g192(HW / 1024, C / 16, BATCH);
    dim3 g576(HW / 1024, C3 / 16, BATCH);

    conv1x1_kernel<1, float><<<g192, blk, 0, stream>>>(x, w_gate, buf_gate, nullptr);
    conv1x1_kernel<0, __hip_bfloat16><<<g576, blk, 0, stream>>>(x, w_qkv, buf_t, nullptr);
    dwconv3x3_kernel<<<dim3((BATCH * C3 * HW) / 256), blk, 0, stream>>>(buf_t, w_depth, buf_qkv);
    attention_mfma_kernel<<<dim3(H, HEADS, BATCH), blk, 0, stream>>>(
        (const ushort_t*)buf_qkv, rpb, buf_att);
    conv1x1_kernel<2, float><<<g192, blk, 0, stream>>>(buf_att, w_pre, buf_y, buf_gate);
    conv1x1_kernel<0, float><<<g192, blk, 0, stream>>>(buf_y, w_out, out, nullptr);
}

// Round 4
// 566.853 us; speedup vs baseline: 1.7914x; 1.2366x over previous
//
#include <hip/hip_runtime.h>
#include <hip/hip_bf16.h>
#include <math.h>

#define BATCH 2
#define C 192
#define H 128
#define W 256
#define HEADS 6
#define HD 32
#define HW (H * W)      // 32768
#define C3 (3 * C)      // 576

typedef unsigned short ushort_t;
using bf16x8 = __attribute__((ext_vector_type(8))) short;
using f32x4  = __attribute__((ext_vector_type(4))) float;

struct __align__(8) bf16x4 { __hip_bfloat16 x, y, z, w; };

static __device__ __forceinline__ float bf2f(__hip_bfloat16 v) {
    return __bfloat162float(v);
}
static __device__ __forceinline__ float bfbits2f(ushort_t u) {
    return __uint_as_float(((unsigned)u) << 16);
}
static __device__ __forceinline__ ushort_t f2bfbits(float f) {
    __hip_bfloat16 h = __float2bfloat16(f);
    return *reinterpret_cast<ushort_t*>(&h);
}

// ---------------------------------------------------------------------------
// conv1x1 (unchanged): out[b,o,p] = sum_c w[o,c] in[b,c,p]
// ---------------------------------------------------------------------------
template <int MODE, typename TOUT>
__global__ __launch_bounds__(256) void conv1x1_kernel(
    const float* __restrict__ in, const float* __restrict__ w,
    TOUT* __restrict__ out, const float* __restrict__ gate)
{
    const int b  = blockIdx.z;
    const int o0 = blockIdx.y * 16;
    const int p  = blockIdx.x * 1024 + threadIdx.x * 4;

    const float* inb = in + (size_t)b * C * HW + p;

    float4 acc[16];
#pragma unroll
    for (int o = 0; o < 16; ++o) acc[o] = make_float4(0.f, 0.f, 0.f, 0.f);

    for (int c = 0; c < C; ++c) {
        const float4 xv = *(const float4*)(inb + (size_t)c * HW);
#pragma unroll
        for (int o = 0; o < 16; ++o) {
            const float wv = w[(size_t)(o0 + o) * C + c];
            acc[o].x += wv * xv.x;
            acc[o].y += wv * xv.y;
            acc[o].z += wv * xv.z;
            acc[o].w += wv * xv.w;
        }
    }

    if (MODE == 1) {
#pragma unroll
        for (int o = 0; o < 16; ++o) {
            float4 v = acc[o];
            v.x = v.x / (1.f + __expf(-v.x));
            v.y = v.y / (1.f + __expf(-v.y));
            v.z = v.z / (1.f + __expf(-v.z));
            v.w = v.w / (1.f + __expf(-v.w));
            acc[o] = v;
        }
    } else if (MODE == 2) {
#pragma unroll
        for (int o = 0; o < 16; ++o) {
            const float4 g = *(const float4*)(gate + (size_t)b * C * HW +
                                              (size_t)(o0 + o) * HW + p);
            acc[o].x *= g.x;
            acc[o].y *= g.y;
            acc[o].z *= g.z;
            acc[o].w *= g.w;
        }
    }

    TOUT* ob = out + (size_t)b * gridDim.y * 16 * HW + p;
#pragma unroll
    for (int o = 0; o < 16; ++o) {
        TOUT* dst = ob + (size_t)(o0 + o) * HW;
        if constexpr (sizeof(TOUT) == 4) {
            *(float4*)dst = acc[o];
        } else {
            bf16x4 v;
            v.x = __float2bfloat16(acc[o].x);
            v.y = __float2bfloat16(acc[o].y);
            v.z = __float2bfloat16(acc[o].z);
            v.w = __float2bfloat16(acc[o].w);
            *(bf16x4*)dst = v;
        }
    }
}

// ---------------------------------------------------------------------------
// depthwise 3x3, vectorized: 8 px/thread. Per row: one aligned 16B ushort8
// load + 2 edge scalars -> 3 vec + 6 scalar loads per 8 outputs (was 72).
// Stores: ushort8 (16B), coalesced. ch wave-uniform -> weights s_load.
// ---------------------------------------------------------------------------
__global__ __launch_bounds__(256) void dwconv3x3_kernel(
    const ushort_t* __restrict__ t, const float* __restrict__ wd,
    ushort_t* __restrict__ out)
{
    const int idx = blockIdx.x * 256 + threadIdx.x;  // [0, BATCH*C3*HW/8)
    const int x8 = idx & 31;                         // chunk-of-8 within row
    const int y  = (idx >> 5) & (H - 1);
    const int ch = (idx >> 12) % C3;
    const int b  = idx / (C3 * HW / 8);
    const int x0 = x8 * 8;

    const ushort_t* tp = t + ((size_t)b * C3 + ch) * HW;
    const float* wp = wd + ch * 9;                   // wave-uniform

    float acc[8];
#pragma unroll
    for (int k = 0; k < 8; ++k) acc[k] = 0.f;

#pragma unroll
    for (int dy = -1; dy <= 1; ++dy) {
        const int yy = y + dy;
        if (yy < 0 || yy >= H) continue;
        const ushort_t* rp = tp + yy * W;

        float v[10];
        v[0] = (x0 > 0)     ? bfbits2f(rp[x0 - 1]) : 0.f;
        v[9] = (x0 + 8 < W) ? bfbits2f(rp[x0 + 8]) : 0.f;
        const bf16x8 mid = *(const bf16x8*)(rp + x0);
#pragma unroll
        for (int k = 0; k < 8; ++k)
            v[k + 1] = bfbits2f((ushort_t)mid[k]);

        const float w0 = wp[(dy + 1) * 3 + 0];
        const float w1 = wp[(dy + 1) * 3 + 1];
        const float w2 = wp[(dy + 1) * 3 + 2];
#pragma unroll
        for (int k = 0; k < 8; ++k)
            acc[k] += v[k] * w0 + v[k + 1] * w1 + v[k + 2] * w2;
    }

    bf16x8 o;
#pragma unroll
    for (int k = 0; k < 8; ++k) o[k] = (short)f2bfbits(acc[k]);
    *(bf16x8*)(out + (size_t)idx * 8) = o;
}

// ---------------------------------------------------------------------------
// MFMA attention (unchanged from R3). One block (4 waves) per (b, y, head).
// ---------------------------------------------------------------------------
__global__ __launch_bounds__(256) void attention_mfma_kernel(
    const ushort_t* __restrict__ qkv, const float* __restrict__ rpb,
    float* __restrict__ out)
{
    const int y    = blockIdx.x;
    const int head = blockIdx.y;
    const int b    = blockIdx.z;
    const int t    = threadIdx.x;
    const int wv   = t >> 6;
    const int lane = t & 63;
    const int quad = lane >> 4;
    const int l16  = lane & 15;

    __shared__ __align__(16) char smem[61952];
    ushort_t* Ks  = (ushort_t*)smem;              // [256][40]
    ushort_t* Vt  = (ushort_t*)(smem + 20480);    // [32][264]
    ushort_t* Qs  = (ushort_t*)(smem + 37376);    // [256][40] -> Pbuf
    ushort_t* rb4 = (ushort_t*)(smem + 57856);    // [4][512]
    float*    Ol  = (float*)smem;                 // [32][257]

    const ushort_t* qp = qkv + (size_t)b * C3 * HW +
                         (size_t)(head * HD) * HW + (size_t)y * W;
    const ushort_t* kp = qp + (size_t)C * HW;
    const ushort_t* vp = kp + (size_t)C * HW;

#pragma unroll
    for (int c = 0; c < HD; ++c) {
        const ushort_t kv = kp[(size_t)c * HW + t];
        const ushort_t qv = qp[(size_t)c * HW + t];
        const ushort_t vv = vp[(size_t)c * HW + t];
        Ks[t * 40 + c]  = kv;
        Qs[t * 40 + c]  = qv;
        Vt[c * 264 + t] = vv;
    }
#pragma unroll
    for (int s = 0; s < 4; ++s) {
        const int k1 = t, k2 = 256 + t;
        const float v1 = (k1 + s < 511) ? rpb[(k1 + s) * HEADS + head] : 0.f;
        const float v2 = (k2 + s < 511) ? rpb[(k2 + s) * HEADS + head] : 0.f;
        rb4[s * 512 + k1] = f2bfbits(v1);
        rb4[s * 512 + k2] = f2bfbits(v2);
    }
    __syncthreads();

    bf16x8 aQ[4];
#pragma unroll
    for (int rt = 0; rt < 4; ++rt) {
        const int row = wv * 64 + rt * 16 + l16;
        aQ[rt] = *(const bf16x8*)&Qs[row * 40 + quad * 8];
    }

    const float scale = 0.17677669529663687f;  // 32^-0.5

    float m_acc[16];
#pragma unroll
    for (int i = 0; i < 16; ++i) m_acc[i] = -1e30f;

    for (int n = 0; n < 16; ++n) {
        const bf16x8 bK = *(const bf16x8*)&Ks[(n * 16 + l16) * 40 + quad * 8];
#pragma unroll
        for (int rt = 0; rt < 4; ++rt) {
            f32x4 s = {0.f, 0.f, 0.f, 0.f};
            s = __builtin_amdgcn_mfma_f32_16x16x32_bf16(aQ[rt], bK, s, 0, 0, 0);
            const int base = wv * 64 + rt * 16 + quad * 4 - (n * 16 + l16) + 255;
            const int r0 = base & 3;
            const uint2 raw = *(const uint2*)(rb4 + r0 * 512 + (base - r0));
            const float b0 = __uint_as_float(raw.x << 16);
            const float b1 = __uint_as_float(raw.x & 0xffff0000u);
            const float b2 = __uint_as_float(raw.y << 16);
            const float b3 = __uint_as_float(raw.y & 0xffff0000u);
            m_acc[rt * 4 + 0] = fmaxf(m_acc[rt * 4 + 0], s[0] * scale + b0);
            m_acc[rt * 4 + 1] = fmaxf(m_acc[rt * 4 + 1], s[1] * scale + b1);
            m_acc[rt * 4 + 2] = fmaxf(m_acc[rt * 4 + 2], s[2] * scale + b2);
            m_acc[rt * 4 + 3] = fmaxf(m_acc[rt * 4 + 3], s[3] * scale + b3);
        }
    }
#pragma unroll
    for (int i = 0; i < 16; ++i) {
        float v = m_acc[i];
        v = fmaxf(v, __shfl_xor(v, 1));
        v = fmaxf(v, __shfl_xor(v, 2));
        v = fmaxf(v, __shfl_xor(v, 4));
        v = fmaxf(v, __shfl_xor(v, 8));
        m_acc[i] = v;
    }

    __syncthreads();
    ushort_t* Pb = Qs + wv * 2560;   // per-wave [64][40] bf16

    float l_acc[16];
#pragma unroll
    for (int i = 0; i < 16; ++i) l_acc[i] = 0.f;
    f32x4 o_acc[4][2];
#pragma unroll
    for (int rt = 0; rt < 4; ++rt)
#pragma unroll
        for (int ct = 0; ct < 2; ++ct)
            o_acc[rt][ct] = f32x4{0.f, 0.f, 0.f, 0.f};

    for (int c2 = 0; c2 < 8; ++c2) {
#pragma unroll
        for (int half = 0; half < 2; ++half) {
            const int n = c2 * 2 + half;
            const bf16x8 bK = *(const bf16x8*)&Ks[(n * 16 + l16) * 40 + quad * 8];
#pragma unroll
            for (int rt = 0; rt < 4; ++rt) {
                f32x4 s = {0.f, 0.f, 0.f, 0.f};
                s = __builtin_amdgcn_mfma_f32_16x16x32_bf16(aQ[rt], bK, s, 0, 0, 0);
                const int base = wv * 64 + rt * 16 + quad * 4 - (n * 16 + l16) + 255;
                const int r0 = base & 3;
                const uint2 raw = *(const uint2*)(rb4 + r0 * 512 + (base - r0));
                const float bia[4] = {
                    __uint_as_float(raw.x << 16),
                    __uint_as_float(raw.x & 0xffff0000u),
                    __uint_as_float(raw.y << 16),
                    __uint_as_float(raw.y & 0xffff0000u)};
#pragma unroll
                for (int reg = 0; reg < 4; ++reg) {
                    const float p = __expf(s[reg] * scale + bia[reg] -
                                           m_acc[rt * 4 + reg]);
                    l_acc[rt * 4 + reg] += p;
                    Pb[(rt * 16 + quad * 4 + reg) * 40 + half * 16 + l16] =
                        f2bfbits(p);
                }
            }
        }
#pragma unroll
        for (int rt = 0; rt < 4; ++rt) {
            const bf16x8 aP = *(const bf16x8*)&Pb[(rt * 16 + l16) * 40 + quad * 8];
#pragma unroll
            for (int ct = 0; ct < 2; ++ct) {
                const bf16x8 bV = *(const bf16x8*)
                    &Vt[(ct * 16 + l16) * 264 + c2 * 32 + quad * 8];
                o_acc[rt][ct] = __builtin_amdgcn_mfma_f32_16x16x32_bf16(
                    aP, bV, o_acc[rt][ct], 0, 0, 0);
            }
        }
    }

#pragma unroll
    for (int i = 0; i < 16; ++i) {
        float v = l_acc[i];
        v += __shfl_xor(v, 1);
        v += __shfl_xor(v, 2);
        v += __shfl_xor(v, 4);
        v += __shfl_xor(v, 8);
        l_acc[i] = 1.f / v;
    }

    __syncthreads();
#pragma unroll
    for (int rt = 0; rt < 4; ++rt) {
        const int i = wv * 64 + rt * 16 + quad * 4;
#pragma unroll
        for (int ct = 0; ct < 2; ++ct) {
            const int c = ct * 16 + l16;
#pragma unroll
            for (int reg = 0; reg < 4; ++reg)
                Ol[c * 257 + i + reg] = o_acc[rt][ct][reg] * l_acc[rt * 4 + reg];
        }
    }
    __syncthreads();

    float* op = out + (size_t)b * C * HW + (size_t)(head * HD) * HW + (size_t)y * W;
#pragma unroll
    for (int c = 0; c < HD; ++c)
        op[(size_t)c * HW + t] = Ol[c * 257 + t];
}

// ---------------------------------------------------------------------------
extern "C" void kernel_launch(void* const* d_in, const int* in_sizes, int n_in,
                              void* d_out, int out_size, void* d_ws, size_t ws_size,
                              hipStream_t stream)
{
    const float* x       = (const float*)d_in[0];
    const float* rpb     = (const float*)d_in[1];
    const float* w_qkv   = (const float*)d_in[2];
    const float* w_depth = (const float*)d_in[3];
    const float* w_pre   = (const float*)d_in[4];
    const float* w_out   = (const float*)d_in[5];
    const float* w_gate  = (const float*)d_in[6];
    float* out = (float*)d_out;

    // workspace (201.3 MB):
    //   [0,            75497472)  t    bf16 [B,3C,H,W]  -> later att f32
    //   [75497472,    150994944)  qkv  bf16 [B,3C,H,W]  -> later y   f32
    //   [150994944,   201326592)  gate f32  [B,C,H,W]
    char* wsb = (char*)d_ws;
    __hip_bfloat16* buf_t    = (__hip_bfloat16*)wsb;
    __hip_bfloat16* buf_qkv  = (__hip_bfloat16*)(wsb + 75497472u);
    float*          buf_gate = (float*)(wsb + 150994944u);
    float*          buf_att  = (float*)wsb;
    float*          buf_y    = (float*)(wsb + 75497472u);

    dim3 blk(256);
    dim3 g192(HW / 1024, C / 16, BATCH);
    dim3 g576(HW / 1024, C3 / 16, BATCH);

    conv1x1_kernel<1, float><<<g192, blk, 0, stream>>>(x, w_gate, buf_gate, nullptr);
    conv1x1_kernel<0, __hip_bfloat16><<<g576, blk, 0, stream>>>(x, w_qkv, buf_t, nullptr);
    dwconv3x3_kernel<<<dim3((BATCH * C3 * HW) / (256 * 8)), blk, 0, stream>>>(
        (const ushort_t*)buf_t, w_depth, (ushort_t*)buf_qkv);
    attention_mfma_kernel<<<dim3(H, HEADS, BATCH), blk, 0, stream>>>(
        (const ushort_t*)buf_qkv, rpb, buf_att);
    conv1x1_kernel<2, float><<<g192, blk, 0, stream>>>(buf_att, w_pre, buf_y, buf_gate);
    conv1x1_kernel<0, float><<<g192, blk, 0, stream>>>(buf_y, w_out, out, nullptr);
}

// Round 5
// 391.062 us; speedup vs baseline: 2.5966x; 1.4495x over previous
//
#include <hip/hip_runtime.h>
#include <hip/hip_bf16.h>
#include <math.h>

#define BATCH 2
#define C 192
#define H 128
#define W 256
#define HEADS 6
#define HD 32
#define HW (H * W)      // 32768
#define C3 (3 * C)      // 576
#define NPX (BATCH * HW)  // 65536

typedef unsigned short ushort_t;
using bf16x8 = __attribute__((ext_vector_type(8))) short;
using f32x4  = __attribute__((ext_vector_type(4))) float;

static __device__ __forceinline__ float bfbits2f(ushort_t u) {
    return __uint_as_float(((unsigned)u) << 16);
}
static __device__ __forceinline__ ushort_t f2bfbits(float f) {
    __hip_bfloat16 h = __float2bfloat16(f);
    return *reinterpret_cast<ushort_t*>(&h);
}

// ---------------------------------------------------------------------------
// prep_w: convert the 4 weight matrices fp32 -> bf16 into one ws region.
// layout (elements): qkv @0 (110592), gate @110592, pre @147456, out @184320.
// grid 216 x 256, one float4 per thread.
// ---------------------------------------------------------------------------
__global__ __launch_bounds__(256) void prep_w_kernel(
    const float* __restrict__ wq, const float* __restrict__ wg,
    const float* __restrict__ wp, const float* __restrict__ wo,
    ushort_t* __restrict__ dst)
{
    const int i = blockIdx.x * 256 + threadIdx.x;   // float4 index, < 55296
    const float* src; int off, base;
    if (i < 27648)      { src = wq; off = i;         base = 0; }
    else if (i < 36864) { src = wg; off = i - 27648; base = 110592; }
    else if (i < 46080) { src = wp; off = i - 36864; base = 147456; }
    else                { src = wo; off = i - 46080; base = 184320; }
    const float4 v = ((const float4*)src)[off];
    ushort4 o;
    o.x = f2bfbits(v.x); o.y = f2bfbits(v.y);
    o.z = f2bfbits(v.z); o.w = f2bfbits(v.w);
    *(ushort4*)(dst + base + off * 4) = o;
}

// ---------------------------------------------------------------------------
// transpose_x: x [B][192][HW] f32 -> x_t [B*HW][192] bf16 (pixel-major).
// Block: 64 px. LDS as uint (bf16 pairs): Xs[px][96 cpairs], stride 97.
// ---------------------------------------------------------------------------
__global__ __launch_bounds__(256) void transpose_x_kernel(
    const float* __restrict__ x, ushort_t* __restrict__ xt)
{
    __shared__ uint Xs[64 * 97];   // 24.8 KB
    const int p0 = blockIdx.x * 64;
    const int b  = p0 >> 15, hw0 = p0 & (HW - 1);
    const int t  = threadIdx.x;

    {
        const int px = t & 63, g = t >> 6;
        const float* xb = x + (size_t)b * C * HW + hw0 + px;
#pragma unroll
        for (int i = 0; i < 24; ++i) {
            const int cp = g + i * 4;   // channel pair 0..95
            const float v0 = xb[(size_t)(2 * cp) * HW];
            const float v1 = xb[(size_t)(2 * cp + 1) * HW];
            Xs[px * 97 + cp] = (uint)f2bfbits(v0) | ((uint)f2bfbits(v1) << 16);
        }
    }
    __syncthreads();
    {
        const int px = t >> 2, grp = t & 3;
        uint* dst = (uint*)(xt + (size_t)(p0 + px) * C) + grp * 24;
        const uint* s = &Xs[px * 97 + grp * 24];
#pragma unroll
        for (int i = 0; i < 6; ++i) {
            uint4 u;
            u.x = s[i * 4 + 0]; u.y = s[i * 4 + 1];
            u.z = s[i * 4 + 2]; u.w = s[i * 4 + 3];
            *(uint4*)(dst + i * 4) = u;
        }
    }
}

// ---------------------------------------------------------------------------
// MFMA conv1x1 GEMM: C[ch][px] = sum_k w[ch][k] * in_t[px][k], K = 192.
// Block: 4 waves, tile M=64 x N=256 (wave: 64x64, 16 accs). No LDS main loop:
// A-frags 16B from w_bf (L2-resident), B-frags 16B from pixel-major in_t.
// grid (Cout/64, NPX/256): m-fastest -> consecutive blocks share B in L2.
// MODE: 0 none, 1 silu, 2 *gate.  OUTKIND: 0 px-major bf16 (stride 192),
// 1 ch-major f32, 2 ch-major bf16 via LDS transpose (coalesced stores).
// ---------------------------------------------------------------------------
template <int MODE, int OUTKIND>
__global__ __launch_bounds__(256) void conv_mfma_kernel(
    const ushort_t* __restrict__ in_t, const ushort_t* __restrict__ w_bf,
    void* __restrict__ outp, const ushort_t* __restrict__ gate, int Cout)
{
    const int m0 = blockIdx.x * 64;
    const int p0 = blockIdx.y * 256;
    const int t  = threadIdx.x;
    const int wv = t >> 6, lane = t & 63, quad = lane >> 4, l16 = lane & 15;

    f32x4 acc[4][4];
#pragma unroll
    for (int rt = 0; rt < 4; ++rt)
#pragma unroll
        for (int ct = 0; ct < 4; ++ct) acc[rt][ct] = f32x4{0.f, 0.f, 0.f, 0.f};

    const ushort_t* wp = w_bf + (size_t)m0 * C + l16 * C + quad * 8;
    const ushort_t* bp = in_t + (size_t)(p0 + wv * 64 + l16) * C + quad * 8;

#pragma unroll 2
    for (int ks = 0; ks < 6; ++ks) {
        bf16x8 aF[4], bF[4];
#pragma unroll
        for (int rt = 0; rt < 4; ++rt)
            aF[rt] = *(const bf16x8*)(wp + rt * 16 * C + ks * 32);
#pragma unroll
        for (int ct = 0; ct < 4; ++ct)
            bF[ct] = *(const bf16x8*)(bp + (size_t)(ct * 16) * C + ks * 32);
#pragma unroll
        for (int rt = 0; rt < 4; ++rt)
#pragma unroll
            for (int ct = 0; ct < 4; ++ct)
                acc[rt][ct] = __builtin_amdgcn_mfma_f32_16x16x32_bf16(
                    aF[rt], bF[ct], acc[rt][ct], 0, 0, 0);
    }

    // ---- epilogue ----
#pragma unroll
    for (int rt = 0; rt < 4; ++rt)
#pragma unroll
        for (int ct = 0; ct < 4; ++ct) {
            f32x4 v = acc[rt][ct];
            if (MODE == 1) {
#pragma unroll
                for (int r = 0; r < 4; ++r)
                    v[r] = v[r] / (1.f + __expf(-v[r]));
            }
            acc[rt][ct] = v;
        }

    if constexpr (OUTKIND == 0) {
        // pixel-major bf16 [px][192]
        ushort_t* ob = (ushort_t*)outp;
#pragma unroll
        for (int rt = 0; rt < 4; ++rt)
#pragma unroll
            for (int ct = 0; ct < 4; ++ct) {
                const int px = p0 + wv * 64 + ct * 16 + l16;
                const int ch = m0 + rt * 16 + quad * 4;
                f32x4 v = acc[rt][ct];
                if (MODE == 2) {
                    const ushort4 g = *(const ushort4*)(gate + (size_t)px * C + ch);
                    v[0] *= bfbits2f(g.x); v[1] *= bfbits2f(g.y);
                    v[2] *= bfbits2f(g.z); v[3] *= bfbits2f(g.w);
                }
                ushort4 o;
                o.x = f2bfbits(v[0]); o.y = f2bfbits(v[1]);
                o.z = f2bfbits(v[2]); o.w = f2bfbits(v[3]);
                *(ushort4*)(ob + (size_t)px * C + ch) = o;
            }
    } else if constexpr (OUTKIND == 1) {
        // channel-major f32 [B][Cout][HW]
        const int bb = p0 >> 15, hw0 = (p0 & (HW - 1)) + wv * 64;
        float* ob = (float*)outp + ((size_t)bb * Cout + m0) * HW + hw0;
#pragma unroll
        for (int rt = 0; rt < 4; ++rt)
#pragma unroll
            for (int ct = 0; ct < 4; ++ct) {
                const f32x4 v = acc[rt][ct];
#pragma unroll
                for (int r = 0; r < 4; ++r)
                    ob[(size_t)(rt * 16 + quad * 4 + r) * HW + ct * 16 + l16] = v[r];
            }
    } else {
        // channel-major bf16 via LDS transpose (stride 268: conflict-light)
        __shared__ ushort_t Cs[64 * 268];   // 34.3 KB
#pragma unroll
        for (int rt = 0; rt < 4; ++rt)
#pragma unroll
            for (int ct = 0; ct < 4; ++ct) {
                const f32x4 v = acc[rt][ct];
                const int px = wv * 64 + ct * 16 + l16;
#pragma unroll
                for (int r = 0; r < 4; ++r)
                    Cs[(rt * 16 + quad * 4 + r) * 268 + px] = f2bfbits(v[r]);
            }
        __syncthreads();
        const int ch = t >> 2, grp = t & 3;
        const int bb = p0 >> 15, hw0 = p0 & (HW - 1);
        ushort_t* ob = (ushort_t*)outp + ((size_t)bb * Cout + m0 + ch) * HW + hw0;
#pragma unroll
        for (int i = 0; i < 8; ++i) {
            const int px = (grp + i * 4) * 8;
            const ushort4 u0 = *(const ushort4*)&Cs[ch * 268 + px];
            const ushort4 u1 = *(const ushort4*)&Cs[ch * 268 + px + 4];
            *(ushort4*)(ob + px)     = u0;
            *(ushort4*)(ob + px + 4) = u1;
        }
    }
}

// ---------------------------------------------------------------------------
// depthwise 3x3 (unchanged from R4): 8 px/thread, ushort8 row loads.
// ---------------------------------------------------------------------------
__global__ __launch_bounds__(256) void dwconv3x3_kernel(
    const ushort_t* __restrict__ t, const float* __restrict__ wd,
    ushort_t* __restrict__ out)
{
    const int idx = blockIdx.x * 256 + threadIdx.x;
    const int x8 = idx & 31;
    const int y  = (idx >> 5) & (H - 1);
    const int ch = (idx >> 12) % C3;
    const int b  = idx / (C3 * HW / 8);
    const int x0 = x8 * 8;

    const ushort_t* tp = t + ((size_t)b * C3 + ch) * HW;
    const float* wp = wd + ch * 9;

    float acc[8];
#pragma unroll
    for (int k = 0; k < 8; ++k) acc[k] = 0.f;

#pragma unroll
    for (int dy = -1; dy <= 1; ++dy) {
        const int yy = y + dy;
        if (yy < 0 || yy >= H) continue;
        const ushort_t* rp = tp + yy * W;

        float v[10];
        v[0] = (x0 > 0)     ? bfbits2f(rp[x0 - 1]) : 0.f;
        v[9] = (x0 + 8 < W) ? bfbits2f(rp[x0 + 8]) : 0.f;
        const bf16x8 mid = *(const bf16x8*)(rp + x0);
#pragma unroll
        for (int k = 0; k < 8; ++k)
            v[k + 1] = bfbits2f((ushort_t)mid[k]);

        const float w0 = wp[(dy + 1) * 3 + 0];
        const float w1 = wp[(dy + 1) * 3 + 1];
        const float w2 = wp[(dy + 1) * 3 + 2];
#pragma unroll
        for (int k = 0; k < 8; ++k)
            acc[k] += v[k] * w0 + v[k + 1] * w1 + v[k + 2] * w2;
    }

    bf16x8 o;
#pragma unroll
    for (int k = 0; k < 8; ++k) o[k] = (short)f2bfbits(acc[k]);
    *(bf16x8*)(out + (size_t)idx * 8) = o;
}

// ---------------------------------------------------------------------------
// MFMA attention (R3 core; epilogue now writes pixel-major bf16 att_t).
// ---------------------------------------------------------------------------
__global__ __launch_bounds__(256) void attention_mfma_kernel(
    const ushort_t* __restrict__ qkv, const float* __restrict__ rpb,
    ushort_t* __restrict__ att)
{
    const int y    = blockIdx.x;
    const int head = blockIdx.y;
    const int b    = blockIdx.z;
    const int t    = threadIdx.x;
    const int wv   = t >> 6;
    const int lane = t & 63;
    const int quad = lane >> 4;
    const int l16  = lane & 15;

    __shared__ __align__(16) char smem[61952];
    ushort_t* Ks  = (ushort_t*)smem;              // [256][40]
    ushort_t* Vt  = (ushort_t*)(smem + 20480);    // [32][264]
    ushort_t* Qs  = (ushort_t*)(smem + 37376);    // [256][40] -> Pbuf
    ushort_t* rb4 = (ushort_t*)(smem + 57856);    // [4][512]
    float*    Ol  = (float*)smem;                 // [32][257]

    const ushort_t* qp = qkv + (size_t)b * C3 * HW +
                         (size_t)(head * HD) * HW + (size_t)y * W;
    const ushort_t* kp = qp + (size_t)C * HW;
    const ushort_t* vp = kp + (size_t)C * HW;

#pragma unroll
    for (int c = 0; c < HD; ++c) {
        const ushort_t kv = kp[(size_t)c * HW + t];
        const ushort_t qv = qp[(size_t)c * HW + t];
        const ushort_t vv = vp[(size_t)c * HW + t];
        Ks[t * 40 + c]  = kv;
        Qs[t * 40 + c]  = qv;
        Vt[c * 264 + t] = vv;
    }
#pragma unroll
    for (int s = 0; s < 4; ++s) {
        const int k1 = t, k2 = 256 + t;
        const float v1 = (k1 + s < 511) ? rpb[(k1 + s) * HEADS + head] : 0.f;
        const float v2 = (k2 + s < 511) ? rpb[(k2 + s) * HEADS + head] : 0.f;
        rb4[s * 512 + k1] = f2bfbits(v1);
        rb4[s * 512 + k2] = f2bfbits(v2);
    }
    __syncthreads();

    bf16x8 aQ[4];
#pragma unroll
    for (int rt = 0; rt < 4; ++rt) {
        const int row = wv * 64 + rt * 16 + l16;
        aQ[rt] = *(const bf16x8*)&Qs[row * 40 + quad * 8];
    }

    const float scale = 0.17677669529663687f;  // 32^-0.5

    float m_acc[16];
#pragma unroll
    for (int i = 0; i < 16; ++i) m_acc[i] = -1e30f;

    for (int n = 0; n < 16; ++n) {
        const bf16x8 bK = *(const bf16x8*)&Ks[(n * 16 + l16) * 40 + quad * 8];
#pragma unroll
        for (int rt = 0; rt < 4; ++rt) {
            f32x4 s = {0.f, 0.f, 0.f, 0.f};
            s = __builtin_amdgcn_mfma_f32_16x16x32_bf16(aQ[rt], bK, s, 0, 0, 0);
            const int base = wv * 64 + rt * 16 + quad * 4 - (n * 16 + l16) + 255;
            const int r0 = base & 3;
            const uint2 raw = *(const uint2*)(rb4 + r0 * 512 + (base - r0));
            const float b0 = __uint_as_float(raw.x << 16);
            const float b1 = __uint_as_float(raw.x & 0xffff0000u);
            const float b2 = __uint_as_float(raw.y << 16);
            const float b3 = __uint_as_float(raw.y & 0xffff0000u);
            m_acc[rt * 4 + 0] = fmaxf(m_acc[rt * 4 + 0], s[0] * scale + b0);
            m_acc[rt * 4 + 1] = fmaxf(m_acc[rt * 4 + 1], s[1] * scale + b1);
            m_acc[rt * 4 + 2] = fmaxf(m_acc[rt * 4 + 2], s[2] * scale + b2);
            m_acc[rt * 4 + 3] = fmaxf(m_acc[rt * 4 + 3], s[3] * scale + b3);
        }
    }
#pragma unroll
    for (int i = 0; i < 16; ++i) {
        float v = m_acc[i];
        v = fmaxf(v, __shfl_xor(v, 1));
        v = fmaxf(v, __shfl_xor(v, 2));
        v = fmaxf(v, __shfl_xor(v, 4));
        v = fmaxf(v, __shfl_xor(v, 8));
        m_acc[i] = v;
    }

    __syncthreads();
    ushort_t* Pb = Qs + wv * 2560;   // per-wave [64][40] bf16

    float l_acc[16];
#pragma unroll
    for (int i = 0; i < 16; ++i) l_acc[i] = 0.f;
    f32x4 o_acc[4][2];
#pragma unroll
    for (int rt = 0; rt < 4; ++rt)
#pragma unroll
        for (int ct = 0; ct < 2; ++ct)
            o_acc[rt][ct] = f32x4{0.f, 0.f, 0.f, 0.f};

    for (int c2 = 0; c2 < 8; ++c2) {
#pragma unroll
        for (int half = 0; half < 2; ++half) {
            const int n = c2 * 2 + half;
            const bf16x8 bK = *(const bf16x8*)&Ks[(n * 16 + l16) * 40 + quad * 8];
#pragma unroll
            for (int rt = 0; rt < 4; ++rt) {
                f32x4 s = {0.f, 0.f, 0.f, 0.f};
                s = __builtin_amdgcn_mfma_f32_16x16x32_bf16(aQ[rt], bK, s, 0, 0, 0);
                const int base = wv * 64 + rt * 16 + quad * 4 - (n * 16 + l16) + 255;
                const int r0 = base & 3;
                const uint2 raw = *(const uint2*)(rb4 + r0 * 512 + (base - r0));
                const float bia[4] = {
                    __uint_as_float(raw.x << 16),
                    __uint_as_float(raw.x & 0xffff0000u),
                    __uint_as_float(raw.y << 16),
                    __uint_as_float(raw.y & 0xffff0000u)};
#pragma unroll
                for (int reg = 0; reg < 4; ++reg) {
                    const float p = __expf(s[reg] * scale + bia[reg] -
                                           m_acc[rt * 4 + reg]);
                    l_acc[rt * 4 + reg] += p;
                    Pb[(rt * 16 + quad * 4 + reg) * 40 + half * 16 + l16] =
                        f2bfbits(p);
                }
            }
        }
#pragma unroll
        for (int rt = 0; rt < 4; ++rt) {
            const bf16x8 aP = *(const bf16x8*)&Pb[(rt * 16 + l16) * 40 + quad * 8];
#pragma unroll
            for (int ct = 0; ct < 2; ++ct) {
                const bf16x8 bV = *(const bf16x8*)
                    &Vt[(ct * 16 + l16) * 264 + c2 * 32 + quad * 8];
                o_acc[rt][ct] = __builtin_amdgcn_mfma_f32_16x16x32_bf16(
                    aP, bV, o_acc[rt][ct], 0, 0, 0);
            }
        }
    }

#pragma unroll
    for (int i = 0; i < 16; ++i) {
        float v = l_acc[i];
        v += __shfl_xor(v, 1);
        v += __shfl_xor(v, 2);
        v += __shfl_xor(v, 4);
        v += __shfl_xor(v, 8);
        l_acc[i] = 1.f / v;
    }

    __syncthreads();
#pragma unroll
    for (int rt = 0; rt < 4; ++rt) {
        const int i = wv * 64 + rt * 16 + quad * 4;
#pragma unroll
        for (int ct = 0; ct < 2; ++ct) {
            const int c = ct * 16 + l16;
#pragma unroll
            for (int reg = 0; reg < 4; ++reg)
                Ol[c * 257 + i + reg] = o_acc[rt][ct][reg] * l_acc[rt * 4 + reg];
        }
    }
    __syncthreads();

    // pixel-major bf16 store: att[(b*HW + y*W + t)*192 + head*32 + c]
    ushort_t* op = att + ((size_t)b * HW + (size_t)y * W + t) * C + head * HD;
#pragma unroll
    for (int g8 = 0; g8 < 4; ++g8) {
        bf16x8 o;
#pragma unroll
        for (int k = 0; k < 8; ++k)
            o[k] = (short)f2bfbits(Ol[(g8 * 8 + k) * 257 + t]);
        *(bf16x8*)(op + g8 * 8) = o;
    }
}

// ---------------------------------------------------------------------------
extern "C" void kernel_launch(void* const* d_in, const int* in_sizes, int n_in,
                              void* d_out, int out_size, void* d_ws, size_t ws_size,
                              hipStream_t stream)
{
    const float* x       = (const float*)d_in[0];
    const float* rpb     = (const float*)d_in[1];
    const float* w_qkv   = (const float*)d_in[2];
    const float* w_depth = (const float*)d_in[3];
    const float* w_pre   = (const float*)d_in[4];
    const float* w_out   = (const float*)d_in[5];
    const float* w_gate  = (const float*)d_in[6];
    float* out = (float*)d_out;

    // workspace layout (176.7 MB), aliased by lifetime:
    //   [0,        442368)     w_bf (4 matrices, bf16)
    //   [524288,   25690112)   gate_t  bf16 [NPX][192]
    //   regionA [25690112, 101187584):
    //       t (ch-major bf16, 75.5MB); later att_t @25690112 (25.2MB),
    //       y_t @50855936 (25.2MB)
    //   regionB [101187584, 176685056):
    //       x_t @101187584 (25.2MB, dead before dwconv); later qkv (75.5MB)
    char* wsb = (char*)d_ws;
    ushort_t* wbf     = (ushort_t*)wsb;
    ushort_t* w_qkv_b = wbf;
    ushort_t* w_gate_b= wbf + 110592;
    ushort_t* w_pre_b = wbf + 147456;
    ushort_t* w_out_b = wbf + 184320;
    ushort_t* gate_t  = (ushort_t*)(wsb + 524288u);
    ushort_t* buf_t   = (ushort_t*)(wsb + 25690112u);
    ushort_t* att_t   = (ushort_t*)(wsb + 25690112u);
    ushort_t* y_t     = (ushort_t*)(wsb + 50855936u);
    ushort_t* buf_qkv = (ushort_t*)(wsb + 101187584u);
    ushort_t* x_t     = (ushort_t*)(wsb + 101187584u);

    dim3 blk(256);

    // 0. weights -> bf16
    prep_w_kernel<<<dim3(216), blk, 0, stream>>>(w_qkv, w_gate, w_pre, w_out, wbf);
    // 1. x -> pixel-major bf16
    transpose_x_kernel<<<dim3(NPX / 64), blk, 0, stream>>>(x, x_t);
    // 2. gate_t = silu(x_t @ w_gate)           [px-major bf16]
    conv_mfma_kernel<1, 0><<<dim3(3, NPX / 256), blk, 0, stream>>>(
        x_t, w_gate_b, gate_t, nullptr, C);
    // 3. t = x_t @ w_qkv                        [ch-major bf16]
    conv_mfma_kernel<0, 2><<<dim3(9, NPX / 256), blk, 0, stream>>>(
        x_t, w_qkv_b, buf_t, nullptr, C3);
    // 4. qkv = depthwise3x3(t)                  [ch-major bf16]
    dwconv3x3_kernel<<<dim3((BATCH * C3 * HW) / (256 * 8)), blk, 0, stream>>>(
        buf_t, w_depth, buf_qkv);
    // 5. att_t = attention(qkv, rpb)            [px-major bf16]
    attention_mfma_kernel<<<dim3(H, HEADS, BATCH), blk, 0, stream>>>(
        buf_qkv, rpb, att_t);
    // 6. y_t = (att_t @ w_pre) * gate_t         [px-major bf16]
    conv_mfma_kernel<2, 0><<<dim3(3, NPX / 256), blk, 0, stream>>>(
        att_t, w_pre_b, y_t, gate_t, C);
    // 7. out = y_t @ w_out                      [ch-major f32]
    conv_mfma_kernel<0, 1><<<dim3(3, NPX / 256), blk, 0, stream>>>(
        y_t, w_out_b, out, nullptr, C);
}

// Round 6
// 375.627 us; speedup vs baseline: 2.7033x; 1.0411x over previous
//
#include <hip/hip_runtime.h>
#include <hip/hip_bf16.h>
#include <math.h>

#define BATCH 2
#define C 192
#define H 128
#define W 256
#define HEADS 6
#define HD 32
#define HW (H * W)      // 32768
#define C3 (3 * C)      // 576
#define NPX (BATCH * HW)  // 65536

typedef unsigned short ushort_t;
using bf16x8 = __attribute__((ext_vector_type(8))) short;
using f32x4  = __attribute__((ext_vector_type(4))) float;

static __device__ __forceinline__ float bfbits2f(ushort_t u) {
    return __uint_as_float(((unsigned)u) << 16);
}
static __device__ __forceinline__ ushort_t f2bfbits(float f) {
    __hip_bfloat16 h = __float2bfloat16(f);
    return *reinterpret_cast<ushort_t*>(&h);
}

// ---------------------------------------------------------------------------
// prep_w: convert the 4 weight matrices fp32 -> bf16 into one ws region.
// ---------------------------------------------------------------------------
__global__ __launch_bounds__(256) void prep_w_kernel(
    const float* __restrict__ wq, const float* __restrict__ wg,
    const float* __restrict__ wp, const float* __restrict__ wo,
    ushort_t* __restrict__ dst)
{
    const int i = blockIdx.x * 256 + threadIdx.x;   // float4 index, < 55296
    const float* src; int off, base;
    if (i < 27648)      { src = wq; off = i;         base = 0; }
    else if (i < 36864) { src = wg; off = i - 27648; base = 110592; }
    else if (i < 46080) { src = wp; off = i - 36864; base = 147456; }
    else                { src = wo; off = i - 46080; base = 184320; }
    const float4 v = ((const float4*)src)[off];
    ushort4 o;
    o.x = f2bfbits(v.x); o.y = f2bfbits(v.y);
    o.z = f2bfbits(v.z); o.w = f2bfbits(v.w);
    *(ushort4*)(dst + base + off * 4) = o;
}

// ---------------------------------------------------------------------------
// transpose_x: x [B][192][HW] f32 -> x_t [B*HW][192] bf16 (pixel-major).
// ---------------------------------------------------------------------------
__global__ __launch_bounds__(256) void transpose_x_kernel(
    const float* __restrict__ x, ushort_t* __restrict__ xt)
{
    __shared__ uint Xs[64 * 97];   // 24.8 KB
    const int p0 = blockIdx.x * 64;
    const int b  = p0 >> 15, hw0 = p0 & (HW - 1);
    const int t  = threadIdx.x;

    {
        const int px = t & 63, g = t >> 6;
        const float* xb = x + (size_t)b * C * HW + hw0 + px;
#pragma unroll
        for (int i = 0; i < 24; ++i) {
            const int cp = g + i * 4;   // channel pair 0..95
            const float v0 = xb[(size_t)(2 * cp) * HW];
            const float v1 = xb[(size_t)(2 * cp + 1) * HW];
            Xs[px * 97 + cp] = (uint)f2bfbits(v0) | ((uint)f2bfbits(v1) << 16);
        }
    }
    __syncthreads();
    {
        const int px = t >> 2, grp = t & 3;
        uint* dst = (uint*)(xt + (size_t)(p0 + px) * C) + grp * 24;
        const uint* s = &Xs[px * 97 + grp * 24];
#pragma unroll
        for (int i = 0; i < 6; ++i) {
            uint4 u;
            u.x = s[i * 4 + 0]; u.y = s[i * 4 + 1];
            u.z = s[i * 4 + 2]; u.w = s[i * 4 + 3];
            *(uint4*)(dst + i * 4) = u;
        }
    }
}

// ---------------------------------------------------------------------------
// MFMA conv1x1 GEMM (unchanged from R5).
// ---------------------------------------------------------------------------
template <int MODE, int OUTKIND>
__global__ __launch_bounds__(256) void conv_mfma_kernel(
    const ushort_t* __restrict__ in_t, const ushort_t* __restrict__ w_bf,
    void* __restrict__ outp, const ushort_t* __restrict__ gate, int Cout)
{
    const int m0 = blockIdx.x * 64;
    const int p0 = blockIdx.y * 256;
    const int t  = threadIdx.x;
    const int wv = t >> 6, lane = t & 63, quad = lane >> 4, l16 = lane & 15;

    f32x4 acc[4][4];
#pragma unroll
    for (int rt = 0; rt < 4; ++rt)
#pragma unroll
        for (int ct = 0; ct < 4; ++ct) acc[rt][ct] = f32x4{0.f, 0.f, 0.f, 0.f};

    const ushort_t* wp = w_bf + (size_t)m0 * C + l16 * C + quad * 8;
    const ushort_t* bp = in_t + (size_t)(p0 + wv * 64 + l16) * C + quad * 8;

#pragma unroll 2
    for (int ks = 0; ks < 6; ++ks) {
        bf16x8 aF[4], bF[4];
#pragma unroll
        for (int rt = 0; rt < 4; ++rt)
            aF[rt] = *(const bf16x8*)(wp + rt * 16 * C + ks * 32);
#pragma unroll
        for (int ct = 0; ct < 4; ++ct)
            bF[ct] = *(const bf16x8*)(bp + (size_t)(ct * 16) * C + ks * 32);
#pragma unroll
        for (int rt = 0; rt < 4; ++rt)
#pragma unroll
            for (int ct = 0; ct < 4; ++ct)
                acc[rt][ct] = __builtin_amdgcn_mfma_f32_16x16x32_bf16(
                    aF[rt], bF[ct], acc[rt][ct], 0, 0, 0);
    }

#pragma unroll
    for (int rt = 0; rt < 4; ++rt)
#pragma unroll
        for (int ct = 0; ct < 4; ++ct) {
            f32x4 v = acc[rt][ct];
            if (MODE == 1) {
#pragma unroll
                for (int r = 0; r < 4; ++r)
                    v[r] = v[r] / (1.f + __expf(-v[r]));
            }
            acc[rt][ct] = v;
        }

    if constexpr (OUTKIND == 0) {
        ushort_t* ob = (ushort_t*)outp;
#pragma unroll
        for (int rt = 0; rt < 4; ++rt)
#pragma unroll
            for (int ct = 0; ct < 4; ++ct) {
                const int px = p0 + wv * 64 + ct * 16 + l16;
                const int ch = m0 + rt * 16 + quad * 4;
                f32x4 v = acc[rt][ct];
                if (MODE == 2) {
                    const ushort4 g = *(const ushort4*)(gate + (size_t)px * C + ch);
                    v[0] *= bfbits2f(g.x); v[1] *= bfbits2f(g.y);
                    v[2] *= bfbits2f(g.z); v[3] *= bfbits2f(g.w);
                }
                ushort4 o;
                o.x = f2bfbits(v[0]); o.y = f2bfbits(v[1]);
                o.z = f2bfbits(v[2]); o.w = f2bfbits(v[3]);
                *(ushort4*)(ob + (size_t)px * C + ch) = o;
            }
    } else if constexpr (OUTKIND == 1) {
        const int bb = p0 >> 15, hw0 = (p0 & (HW - 1)) + wv * 64;
        float* ob = (float*)outp + ((size_t)bb * Cout + m0) * HW + hw0;
#pragma unroll
        for (int rt = 0; rt < 4; ++rt)
#pragma unroll
            for (int ct = 0; ct < 4; ++ct) {
                const f32x4 v = acc[rt][ct];
#pragma unroll
                for (int r = 0; r < 4; ++r)
                    ob[(size_t)(rt * 16 + quad * 4 + r) * HW + ct * 16 + l16] = v[r];
            }
    } else {
        __shared__ ushort_t Cs[64 * 268];   // 34.3 KB
#pragma unroll
        for (int rt = 0; rt < 4; ++rt)
#pragma unroll
            for (int ct = 0; ct < 4; ++ct) {
                const f32x4 v = acc[rt][ct];
                const int px = wv * 64 + ct * 16 + l16;
#pragma unroll
                for (int r = 0; r < 4; ++r)
                    Cs[(rt * 16 + quad * 4 + r) * 268 + px] = f2bfbits(v[r]);
            }
        __syncthreads();
        const int ch = t >> 2, grp = t & 3;
        const int bb = p0 >> 15, hw0 = p0 & (HW - 1);
        ushort_t* ob = (ushort_t*)outp + ((size_t)bb * Cout + m0 + ch) * HW + hw0;
#pragma unroll
        for (int i = 0; i < 8; ++i) {
            const int px = (grp + i * 4) * 8;
            const ushort4 u0 = *(const ushort4*)&Cs[ch * 268 + px];
            const ushort4 u1 = *(const ushort4*)&Cs[ch * 268 + px + 4];
            *(ushort4*)(ob + px)     = u0;
            *(ushort4*)(ob + px + 4) = u1;
        }
    }
}

// ---------------------------------------------------------------------------
// depthwise 3x3 (unchanged from R4).
// ---------------------------------------------------------------------------
__global__ __launch_bounds__(256) void dwconv3x3_kernel(
    const ushort_t* __restrict__ t, const float* __restrict__ wd,
    ushort_t* __restrict__ out)
{
    const int idx = blockIdx.x * 256 + threadIdx.x;
    const int x8 = idx & 31;
    const int y  = (idx >> 5) & (H - 1);
    const int ch = (idx >> 12) % C3;
    const int b  = idx / (C3 * HW / 8);
    const int x0 = x8 * 8;

    const ushort_t* tp = t + ((size_t)b * C3 + ch) * HW;
    const float* wp = wd + ch * 9;

    float acc[8];
#pragma unroll
    for (int k = 0; k < 8; ++k) acc[k] = 0.f;

#pragma unroll
    for (int dy = -1; dy <= 1; ++dy) {
        const int yy = y + dy;
        if (yy < 0 || yy >= H) continue;
        const ushort_t* rp = tp + yy * W;

        float v[10];
        v[0] = (x0 > 0)     ? bfbits2f(rp[x0 - 1]) : 0.f;
        v[9] = (x0 + 8 < W) ? bfbits2f(rp[x0 + 8]) : 0.f;
        const bf16x8 mid = *(const bf16x8*)(rp + x0);
#pragma unroll
        for (int k = 0; k < 8; ++k)
            v[k + 1] = bfbits2f((ushort_t)mid[k]);

        const float w0 = wp[(dy + 1) * 3 + 0];
        const float w1 = wp[(dy + 1) * 3 + 1];
        const float w2 = wp[(dy + 1) * 3 + 2];
#pragma unroll
        for (int k = 0; k < 8; ++k)
            acc[k] += v[k] * w0 + v[k + 1] * w1 + v[k + 2] * w2;
    }

    bf16x8 o;
#pragma unroll
    for (int k = 0; k < 8; ++k) o[k] = (short)f2bfbits(acc[k]);
    *(bf16x8*)(out + (size_t)idx * 8) = o;
}

// ---------------------------------------------------------------------------
// MFMA attention, SINGLE PASS (no max subtraction — scores are O(10),
// fp32 exp overflows only past ~88, so softmax w/o shift is exact here).
// Bias enters as the MFMA C-operand; scale folded into Q at staging.
// One block (4 waves) per (b, y, head); wave owns 64 query rows.
// LDS map unchanged from R5 (61952 B).
// ---------------------------------------------------------------------------
__global__ __launch_bounds__(256) void attention_mfma_kernel(
    const ushort_t* __restrict__ qkv, const float* __restrict__ rpb,
    ushort_t* __restrict__ att)
{
    const int y    = blockIdx.x;
    const int head = blockIdx.y;
    const int b    = blockIdx.z;
    const int t    = threadIdx.x;
    const int wv   = t >> 6;
    const int lane = t & 63;
    const int quad = lane >> 4;
    const int l16  = lane & 15;

    __shared__ __align__(16) char smem[61952];
    ushort_t* Ks  = (ushort_t*)smem;              // [256][40]
    ushort_t* Vt  = (ushort_t*)(smem + 20480);    // [32][264]
    ushort_t* Qs  = (ushort_t*)(smem + 37376);    // [256][40] -> Pbuf
    ushort_t* rb4 = (ushort_t*)(smem + 57856);    // [4][512]
    float*    Ol  = (float*)smem;                 // [32][257]

    const ushort_t* qp = qkv + (size_t)b * C3 * HW +
                         (size_t)(head * HD) * HW + (size_t)y * W;
    const ushort_t* kp = qp + (size_t)C * HW;
    const ushort_t* vp = kp + (size_t)C * HW;

    const float scale = 0.17677669529663687f;  // 32^-0.5

    // ---- stage Q (pre-scaled), K, V ----
#pragma unroll
    for (int c = 0; c < HD; ++c) {
        const ushort_t kv = kp[(size_t)c * HW + t];
        const ushort_t qv = qp[(size_t)c * HW + t];
        const ushort_t vv = vp[(size_t)c * HW + t];
        Ks[t * 40 + c]  = kv;
        Qs[t * 40 + c]  = f2bfbits(bfbits2f(qv) * scale);
        Vt[c * 264 + t] = vv;
    }
    // staggered bias copies: rb4[s][k] = bf16(rpb[k+s]) -> aligned b64 loads
#pragma unroll
    for (int s = 0; s < 4; ++s) {
        const int k1 = t, k2 = 256 + t;
        const float v1 = (k1 + s < 511) ? rpb[(k1 + s) * HEADS + head] : 0.f;
        const float v2 = (k2 + s < 511) ? rpb[(k2 + s) * HEADS + head] : 0.f;
        rb4[s * 512 + k1] = f2bfbits(v1);
        rb4[s * 512 + k2] = f2bfbits(v2);
    }
    __syncthreads();

    // ---- A-fragments of Q ----
    bf16x8 aQ[4];
#pragma unroll
    for (int rt = 0; rt < 4; ++rt) {
        const int row = wv * 64 + rt * 16 + l16;
        aQ[rt] = *(const bf16x8*)&Qs[row * 40 + quad * 8];
    }
    __syncthreads();   // all waves read their Q frags -> Qs reusable as Pbuf
    ushort_t* Pb = Qs + wv * 2560;   // per-wave [64][40] bf16

    float l_acc[16];
#pragma unroll
    for (int i = 0; i < 16; ++i) l_acc[i] = 0.f;
    f32x4 o_acc[4][2];
#pragma unroll
    for (int rt = 0; rt < 4; ++rt)
#pragma unroll
        for (int ct = 0; ct < 2; ++ct)
            o_acc[rt][ct] = f32x4{0.f, 0.f, 0.f, 0.f};

    for (int c2 = 0; c2 < 8; ++c2) {       // 32 key-columns per step
#pragma unroll
        for (int half = 0; half < 2; ++half) {
            const int n = c2 * 2 + half;
            const bf16x8 bK = *(const bf16x8*)&Ks[(n * 16 + l16) * 40 + quad * 8];
#pragma unroll
            for (int rt = 0; rt < 4; ++rt) {
                // bias for rows (base..base+3), col fixed -> C-operand init
                const int base = wv * 64 + rt * 16 + quad * 4 - (n * 16 + l16) + 255;
                const int r0 = base & 3;
                const uint2 raw = *(const uint2*)(rb4 + r0 * 512 + (base - r0));
                f32x4 s;
                s[0] = __uint_as_float(raw.x << 16);
                s[1] = __uint_as_float(raw.x & 0xffff0000u);
                s[2] = __uint_as_float(raw.y << 16);
                s[3] = __uint_as_float(raw.y & 0xffff0000u);
                s = __builtin_amdgcn_mfma_f32_16x16x32_bf16(aQ[rt], bK, s, 0, 0, 0);
#pragma unroll
                for (int reg = 0; reg < 4; ++reg) {
                    const float p = __expf(s[reg]);
                    l_acc[rt * 4 + reg] += p;
                    Pb[(rt * 16 + quad * 4 + reg) * 40 + half * 16 + l16] =
                        f2bfbits(p);
                }
            }
        }
        // PV over this 32-column chunk
#pragma unroll
        for (int rt = 0; rt < 4; ++rt) {
            const bf16x8 aP = *(const bf16x8*)&Pb[(rt * 16 + l16) * 40 + quad * 8];
#pragma unroll
            for (int ct = 0; ct < 2; ++ct) {
                const bf16x8 bV = *(const bf16x8*)
                    &Vt[(ct * 16 + l16) * 264 + c2 * 32 + quad * 8];
                o_acc[rt][ct] = __builtin_amdgcn_mfma_f32_16x16x32_bf16(
                    aP, bV, o_acc[rt][ct], 0, 0, 0);
            }
        }
    }

    // ---- denominators (butterfly sum over the 16 col-lanes) ----
#pragma unroll
    for (int i = 0; i < 16; ++i) {
        float v = l_acc[i];
        v += __shfl_xor(v, 1);
        v += __shfl_xor(v, 2);
        v += __shfl_xor(v, 4);
        v += __shfl_xor(v, 8);
        l_acc[i] = 1.f / v;
    }

    __syncthreads();   // done with Ks/Vt -> reuse as Ol
#pragma unroll
    for (int rt = 0; rt < 4; ++rt) {
        const int i = wv * 64 + rt * 16 + quad * 4;
#pragma unroll
        for (int ct = 0; ct < 2; ++ct) {
            const int c = ct * 16 + l16;
#pragma unroll
            for (int reg = 0; reg < 4; ++reg)
                Ol[c * 257 + i + reg] = o_acc[rt][ct][reg] * l_acc[rt * 4 + reg];
        }
    }
    __syncthreads();

    // pixel-major bf16 store: att[(b*HW + y*W + t)*192 + head*32 + c]
    ushort_t* op = att + ((size_t)b * HW + (size_t)y * W + t) * C + head * HD;
#pragma unroll
    for (int g8 = 0; g8 < 4; ++g8) {
        bf16x8 o;
#pragma unroll
        for (int k = 0; k < 8; ++k)
            o[k] = (short)f2bfbits(Ol[(g8 * 8 + k) * 257 + t]);
        *(bf16x8*)(op + g8 * 8) = o;
    }
}

// ---------------------------------------------------------------------------
extern "C" void kernel_launch(void* const* d_in, const int* in_sizes, int n_in,
                              void* d_out, int out_size, void* d_ws, size_t ws_size,
                              hipStream_t stream)
{
    const float* x       = (const float*)d_in[0];
    const float* rpb     = (const float*)d_in[1];
    const float* w_qkv   = (const float*)d_in[2];
    const float* w_depth = (const float*)d_in[3];
    const float* w_pre   = (const float*)d_in[4];
    const float* w_out   = (const float*)d_in[5];
    const float* w_gate  = (const float*)d_in[6];
    float* out = (float*)d_out;

    // workspace layout (176.7 MB), aliased by lifetime (as R5):
    char* wsb = (char*)d_ws;
    ushort_t* wbf     = (ushort_t*)wsb;
    ushort_t* w_qkv_b = wbf;
    ushort_t* w_gate_b= wbf + 110592;
    ushort_t* w_pre_b = wbf + 147456;
    ushort_t* w_out_b = wbf + 184320;
    ushort_t* gate_t  = (ushort_t*)(wsb + 524288u);
    ushort_t* buf_t   = (ushort_t*)(wsb + 25690112u);
    ushort_t* att_t   = (ushort_t*)(wsb + 25690112u);
    ushort_t* y_t     = (ushort_t*)(wsb + 50855936u);
    ushort_t* buf_qkv = (ushort_t*)(wsb + 101187584u);
    ushort_t* x_t     = (ushort_t*)(wsb + 101187584u);

    dim3 blk(256);

    prep_w_kernel<<<dim3(216), blk, 0, stream>>>(w_qkv, w_gate, w_pre, w_out, wbf);
    transpose_x_kernel<<<dim3(NPX / 64), blk, 0, stream>>>(x, x_t);
    conv_mfma_kernel<1, 0><<<dim3(3, NPX / 256), blk, 0, stream>>>(
        x_t, w_gate_b, gate_t, nullptr, C);
    conv_mfma_kernel<0, 2><<<dim3(9, NPX / 256), blk, 0, stream>>>(
        x_t, w_qkv_b, buf_t, nullptr, C3);
    dwconv3x3_kernel<<<dim3((BATCH * C3 * HW) / (256 * 8)), blk, 0, stream>>>(
        buf_t, w_depth, buf_qkv);
    attention_mfma_kernel<<<dim3(H, HEADS, BATCH), blk, 0, stream>>>(
        buf_qkv, rpb, att_t);
    conv_mfma_kernel<2, 0><<<dim3(3, NPX / 256), blk, 0, stream>>>(
        att_t, w_pre_b, y_t, gate_t, C);
    conv_mfma_kernel<0, 1><<<dim3(3, NPX / 256), blk, 0, stream>>>(
        y_t, w_out_b, out, nullptr, C);
}

// Round 7
// 373.468 us; speedup vs baseline: 2.7189x; 1.0058x over previous
//
#include <hip/hip_runtime.h>
#include <hip/hip_bf16.h>
#include <math.h>

#define BATCH 2
#define C 192
#define H 128
#define W 256
#define HEADS 6
#define HD 32
#define HW (H * W)      // 32768
#define C3 (3 * C)      // 576
#define NPX (BATCH * HW)  // 65536

typedef unsigned short ushort_t;
using bf16x8 = __attribute__((ext_vector_type(8))) short;
using f32x4  = __attribute__((ext_vector_type(4))) float;

static __device__ __forceinline__ float bfbits2f(ushort_t u) {
    return __uint_as_float(((unsigned)u) << 16);
}
static __device__ __forceinline__ ushort_t f2bfbits(float f) {
    __hip_bfloat16 h = __float2bfloat16(f);
    return *reinterpret_cast<ushort_t*>(&h);
}

// ---------------------------------------------------------------------------
// prep_w: fp32 -> bf16 weights; q-rows of w_qkv pre-scaled by 32^-0.5
// (depthwise conv is linear per-channel, so the scale commutes through it).
// ---------------------------------------------------------------------------
__global__ __launch_bounds__(256) void prep_w_kernel(
    const float* __restrict__ wq, const float* __restrict__ wg,
    const float* __restrict__ wp, const float* __restrict__ wo,
    ushort_t* __restrict__ dst)
{
    const int i = blockIdx.x * 256 + threadIdx.x;   // float4 index, < 55296
    const float* src; int off, base;
    if (i < 27648)      { src = wq; off = i;         base = 0; }
    else if (i < 36864) { src = wg; off = i - 27648; base = 110592; }
    else if (i < 46080) { src = wp; off = i - 36864; base = 147456; }
    else                { src = wo; off = i - 46080; base = 184320; }
    float4 v = ((const float4*)src)[off];
    if (i < 9216) {   // w_qkv rows 0..191 (the q projection)
        const float sc = 0.17677669529663687f;
        v.x *= sc; v.y *= sc; v.z *= sc; v.w *= sc;
    }
    ushort4 o;
    o.x = f2bfbits(v.x); o.y = f2bfbits(v.y);
    o.z = f2bfbits(v.z); o.w = f2bfbits(v.w);
    *(ushort4*)(dst + base + off * 4) = o;
}

// ---------------------------------------------------------------------------
// transpose_x: x [B][192][HW] f32 -> x_t [B*HW][192] bf16 (pixel-major).
// ---------------------------------------------------------------------------
__global__ __launch_bounds__(256) void transpose_x_kernel(
    const float* __restrict__ x, ushort_t* __restrict__ xt)
{
    __shared__ uint Xs[64 * 97];   // 24.8 KB
    const int p0 = blockIdx.x * 64;
    const int b  = p0 >> 15, hw0 = p0 & (HW - 1);
    const int t  = threadIdx.x;

    {
        const int px = t & 63, g = t >> 6;
        const float* xb = x + (size_t)b * C * HW + hw0 + px;
#pragma unroll
        for (int i = 0; i < 24; ++i) {
            const int cp = g + i * 4;   // channel pair 0..95
            const float v0 = xb[(size_t)(2 * cp) * HW];
            const float v1 = xb[(size_t)(2 * cp + 1) * HW];
            Xs[px * 97 + cp] = (uint)f2bfbits(v0) | ((uint)f2bfbits(v1) << 16);
        }
    }
    __syncthreads();
    {
        const int px = t >> 2, grp = t & 3;
        uint* dst = (uint*)(xt + (size_t)(p0 + px) * C) + grp * 24;
        const uint* s = &Xs[px * 97 + grp * 24];
#pragma unroll
        for (int i = 0; i < 6; ++i) {
            uint4 u;
            u.x = s[i * 4 + 0]; u.y = s[i * 4 + 1];
            u.z = s[i * 4 + 2]; u.w = s[i * 4 + 3];
            *(uint4*)(dst + i * 4) = u;
        }
    }
}

// ---------------------------------------------------------------------------
// MFMA conv1x1 GEMM, XCD-swizzled 1-D grid (MT*256 blocks).
// Decode keeps all MT m-blocks of a px-tile on one XCD (lin mod 8 fixed)
// so the shared B-tile is fetched once per XCD, not per block.
// OUTKIND 0: px-major bf16 [px][ostride]; 1: ch-major f32 (final output).
// ---------------------------------------------------------------------------
template <int MODE, int OUTKIND, int MT>
__global__ __launch_bounds__(256) void conv_mfma_kernel(
    const ushort_t* __restrict__ in_t, const ushort_t* __restrict__ w_bf,
    void* __restrict__ outp, const ushort_t* __restrict__ gate, int ostride)
{
    const int lin = blockIdx.x;
    const int xcd = lin & 7;
    const int jj  = lin >> 3;
    const int pin = jj / MT;            // 0..31
    const int m   = jj - pin * MT;      // 0..MT-1
    const int m0  = m * 64;
    const int p0  = (xcd * 32 + pin) * 256;

    const int t  = threadIdx.x;
    const int wv = t >> 6, lane = t & 63, quad = lane >> 4, l16 = lane & 15;

    f32x4 acc[4][4];
#pragma unroll
    for (int rt = 0; rt < 4; ++rt)
#pragma unroll
        for (int ct = 0; ct < 4; ++ct) acc[rt][ct] = f32x4{0.f, 0.f, 0.f, 0.f};

    const ushort_t* wp = w_bf + (size_t)(m0 + l16) * C + quad * 8;
    const ushort_t* bp = in_t + (size_t)(p0 + wv * 64 + l16) * C + quad * 8;

#pragma unroll 2
    for (int ks = 0; ks < 6; ++ks) {
        bf16x8 aF[4], bF[4];
#pragma unroll
        for (int rt = 0; rt < 4; ++rt)
            aF[rt] = *(const bf16x8*)(wp + (size_t)(rt * 16) * C + ks * 32);
#pragma unroll
        for (int ct = 0; ct < 4; ++ct)
            bF[ct] = *(const bf16x8*)(bp + (size_t)(ct * 16) * C + ks * 32);
#pragma unroll
        for (int rt = 0; rt < 4; ++rt)
#pragma unroll
            for (int ct = 0; ct < 4; ++ct)
                acc[rt][ct] = __builtin_amdgcn_mfma_f32_16x16x32_bf16(
                    aF[rt], bF[ct], acc[rt][ct], 0, 0, 0);
    }

#pragma unroll
    for (int rt = 0; rt < 4; ++rt)
#pragma unroll
        for (int ct = 0; ct < 4; ++ct) {
            f32x4 v = acc[rt][ct];
            if (MODE == 1) {
#pragma unroll
                for (int r = 0; r < 4; ++r)
                    v[r] = v[r] / (1.f + __expf(-v[r]));
            }
            acc[rt][ct] = v;
        }

    if constexpr (OUTKIND == 0) {
        ushort_t* ob = (ushort_t*)outp;
#pragma unroll
        for (int rt = 0; rt < 4; ++rt)
#pragma unroll
            for (int ct = 0; ct < 4; ++ct) {
                const int px = p0 + wv * 64 + ct * 16 + l16;
                const int ch = m0 + rt * 16 + quad * 4;
                f32x4 v = acc[rt][ct];
                if (MODE == 2) {
                    const ushort4 g = *(const ushort4*)(gate + (size_t)px * C + ch);
                    v[0] *= bfbits2f(g.x); v[1] *= bfbits2f(g.y);
                    v[2] *= bfbits2f(g.z); v[3] *= bfbits2f(g.w);
                }
                ushort4 o;
                o.x = f2bfbits(v[0]); o.y = f2bfbits(v[1]);
                o.z = f2bfbits(v[2]); o.w = f2bfbits(v[3]);
                *(ushort4*)(ob + (size_t)px * ostride + ch) = o;
            }
    } else {
        // channel-major f32 [B][192][HW] (final output)
        const int bb = p0 >> 15, hw0 = (p0 & (HW - 1)) + wv * 64;
        float* ob = (float*)outp + ((size_t)bb * C + m0) * HW + hw0;
#pragma unroll
        for (int rt = 0; rt < 4; ++rt)
#pragma unroll
            for (int ct = 0; ct < 4; ++ct) {
                const f32x4 v = acc[rt][ct];
#pragma unroll
                for (int r = 0; r < 4; ++r)
                    ob[(size_t)(rt * 16 + quad * 4 + r) * HW + ct * 16 + l16] = v[r];
            }
    }
}

// ---------------------------------------------------------------------------
// depthwise 3x3, pixel-major [px][576]. grid (NPX/128, 9); block 256.
// Thread: 8 channels x 4 consecutive px. Weights (64 ch x 9) staged in LDS.
// Loads: 6 positions x 3 rows x 16B bf16x8; lanes 0..7 = 128B contiguous.
// ---------------------------------------------------------------------------
__global__ __launch_bounds__(256) void dwconv3x3_px_kernel(
    const ushort_t* __restrict__ tin, const float* __restrict__ wd,
    ushort_t* __restrict__ out)
{
    __shared__ float wloc[576];          // 64 ch x 9 taps
    const int cb  = blockIdx.y;          // 64-ch block, 0..8
    const int tid = threadIdx.x;
    if (tid < 144)
        *(float4*)&wloc[tid * 4] = *(const float4*)(wd + cb * 576 + tid * 4);
    __syncthreads();

    const int chloc = (tid & 7) * 8;                     // local ch base
    const int px = blockIdx.x * 128 + (tid >> 3) * 4;    // first output px
    const int x0 = px & (W - 1);
    const int y  = (px >> 8) & (H - 1);

    const ushort_t* tb = tin + (size_t)px * C3 + cb * 64 + chloc;

    float acc[4][8];
#pragma unroll
    for (int i = 0; i < 4; ++i)
#pragma unroll
        for (int k = 0; k < 8; ++k) acc[i][k] = 0.f;

#pragma unroll
    for (int dy = -1; dy <= 1; ++dy) {
        const int yy = y + dy;
        if (yy < 0 || yy >= H) continue;
        const ushort_t* rp = tb + (ptrdiff_t)dy * W * C3;

        float f[6][8];
#pragma unroll
        for (int d = 0; d < 6; ++d) {
            const int xx = x0 + d - 1;
            if (xx < 0 || xx >= W) {
#pragma unroll
                for (int k = 0; k < 8; ++k) f[d][k] = 0.f;
            } else {
                const bf16x8 v = *(const bf16x8*)(rp + (ptrdiff_t)(d - 1) * C3);
#pragma unroll
                for (int k = 0; k < 8; ++k) f[d][k] = bfbits2f((ushort_t)v[k]);
            }
        }
#pragma unroll
        for (int k = 0; k < 8; ++k) {
            const float* wk = &wloc[(chloc + k) * 9 + (dy + 1) * 3];
            const float w0 = wk[0], w1 = wk[1], w2 = wk[2];
#pragma unroll
            for (int i = 0; i < 4; ++i)
                acc[i][k] += f[i][k] * w0 + f[i + 1][k] * w1 + f[i + 2][k] * w2;
        }
    }

    ushort_t* ob = out + (size_t)px * C3 + cb * 64 + chloc;
#pragma unroll
    for (int i = 0; i < 4; ++i) {
        bf16x8 o;
#pragma unroll
        for (int k = 0; k < 8; ++k) o[k] = (short)f2bfbits(acc[i][k]);
        *(bf16x8*)(ob + (size_t)i * C3) = o;
    }
}

// ---------------------------------------------------------------------------
// MFMA attention, single pass (R6 core). Input qkv is px-major [px][576]
// (q ch 0..191 pre-scaled, k 192..383, v 384..575): staging is 12 x 16B
// loads per thread. Output px-major bf16 [px][192].
// ---------------------------------------------------------------------------
__global__ __launch_bounds__(256) void attention_mfma_kernel(
    const ushort_t* __restrict__ qkv, const float* __restrict__ rpb,
    ushort_t* __restrict__ att)
{
    const int y    = blockIdx.x;
    const int head = blockIdx.y;
    const int b    = blockIdx.z;
    const int t    = threadIdx.x;
    const int wv   = t >> 6;
    const int lane = t & 63;
    const int quad = lane >> 4;
    const int l16  = lane & 15;

    __shared__ __align__(16) char smem[61952];
    ushort_t* Ks  = (ushort_t*)smem;              // [256][40]
    ushort_t* Vt  = (ushort_t*)(smem + 20480);    // [32][264]
    ushort_t* Qs  = (ushort_t*)(smem + 37376);    // [256][40] -> Pbuf
    ushort_t* rb4 = (ushort_t*)(smem + 57856);    // [4][512]
    float*    Ol  = (float*)smem;                 // [32][257]

    // ---- stage Q, K, V from the px-major row ----
    const ushort_t* rowp = qkv + ((size_t)b * HW + (size_t)y * W + t) * C3 +
                           head * HD;
    bf16x8 vfr[4];
#pragma unroll
    for (int g = 0; g < 4; ++g) {
        *(bf16x8*)&Qs[t * 40 + g * 8] = *(const bf16x8*)(rowp + g * 8);
        *(bf16x8*)&Ks[t * 40 + g * 8] = *(const bf16x8*)(rowp + C + g * 8);
        vfr[g] = *(const bf16x8*)(rowp + 2 * C + g * 8);
    }
#pragma unroll
    for (int g = 0; g < 4; ++g)
#pragma unroll
        for (int k = 0; k < 8; ++k)
            Vt[(g * 8 + k) * 264 + t] = (ushort_t)vfr[g][k];

    // staggered bias copies -> aligned b64 loads
#pragma unroll
    for (int s = 0; s < 4; ++s) {
        const int k1 = t, k2 = 256 + t;
        const float v1 = (k1 + s < 511) ? rpb[(k1 + s) * HEADS + head] : 0.f;
        const float v2 = (k2 + s < 511) ? rpb[(k2 + s) * HEADS + head] : 0.f;
        rb4[s * 512 + k1] = f2bfbits(v1);
        rb4[s * 512 + k2] = f2bfbits(v2);
    }
    __syncthreads();

    bf16x8 aQ[4];
#pragma unroll
    for (int rt = 0; rt < 4; ++rt) {
        const int row = wv * 64 + rt * 16 + l16;
        aQ[rt] = *(const bf16x8*)&Qs[row * 40 + quad * 8];
    }
    __syncthreads();   // Qs reusable as Pbuf
    ushort_t* Pb = Qs + wv * 2560;   // per-wave [64][40] bf16

    float l_acc[16];
#pragma unroll
    for (int i = 0; i < 16; ++i) l_acc[i] = 0.f;
    f32x4 o_acc[4][2];
#pragma unroll
    for (int rt = 0; rt < 4; ++rt)
#pragma unroll
        for (int ct = 0; ct < 2; ++ct)
            o_acc[rt][ct] = f32x4{0.f, 0.f, 0.f, 0.f};

    for (int c2 = 0; c2 < 8; ++c2) {       // 32 key-columns per step
#pragma unroll
        for (int half = 0; half < 2; ++half) {
            const int n = c2 * 2 + half;
            const bf16x8 bK = *(const bf16x8*)&Ks[(n * 16 + l16) * 40 + quad * 8];
#pragma unroll
            for (int rt = 0; rt < 4; ++rt) {
                const int base = wv * 64 + rt * 16 + quad * 4 - (n * 16 + l16) + 255;
                const int r0 = base & 3;
                const uint2 raw = *(const uint2*)(rb4 + r0 * 512 + (base - r0));
                f32x4 s;
                s[0] = __uint_as_float(raw.x << 16);
                s[1] = __uint_as_float(raw.x & 0xffff0000u);
                s[2] = __uint_as_float(raw.y << 16);
                s[3] = __uint_as_float(raw.y & 0xffff0000u);
                s = __builtin_amdgcn_mfma_f32_16x16x32_bf16(aQ[rt], bK, s, 0, 0, 0);
#pragma unroll
                for (int reg = 0; reg < 4; ++reg) {
                    const float p = __expf(s[reg]);
                    l_acc[rt * 4 + reg] += p;
                    Pb[(rt * 16 + quad * 4 + reg) * 40 + half * 16 + l16] =
                        f2bfbits(p);
                }
            }
        }
#pragma unroll
        for (int rt = 0; rt < 4; ++rt) {
            const bf16x8 aP = *(const bf16x8*)&Pb[(rt * 16 + l16) * 40 + quad * 8];
#pragma unroll
            for (int ct = 0; ct < 2; ++ct) {
                const bf16x8 bV = *(const bf16x8*)
                    &Vt[(ct * 16 + l16) * 264 + c2 * 32 + quad * 8];
                o_acc[rt][ct] = __builtin_amdgcn_mfma_f32_16x16x32_bf16(
                    aP, bV, o_acc[rt][ct], 0, 0, 0);
            }
        }
    }

#pragma unroll
    for (int i = 0; i < 16; ++i) {
        float v = l_acc[i];
        v += __shfl_xor(v, 1);
        v += __shfl_xor(v, 2);
        v += __shfl_xor(v, 4);
        v += __shfl_xor(v, 8);
        l_acc[i] = 1.f / v;
    }

    __syncthreads();   // done with Ks/Vt -> reuse as Ol
#pragma unroll
    for (int rt = 0; rt < 4; ++rt) {
        const int i = wv * 64 + rt * 16 + quad * 4;
#pragma unroll
        for (int ct = 0; ct < 2; ++ct) {
            const int c = ct * 16 + l16;
#pragma unroll
            for (int reg = 0; reg < 4; ++reg)
                Ol[c * 257 + i + reg] = o_acc[rt][ct][reg] * l_acc[rt * 4 + reg];
        }
    }
    __syncthreads();

    // pixel-major bf16 store: att[(b*HW + y*W + t)*192 + head*32 + c]
    ushort_t* op = att + ((size_t)b * HW + (size_t)y * W + t) * C + head * HD;
#pragma unroll
    for (int g8 = 0; g8 < 4; ++g8) {
        bf16x8 o;
#pragma unroll
        for (int k = 0; k < 8; ++k)
            o[k] = (short)f2bfbits(Ol[(g8 * 8 + k) * 257 + t]);
        *(bf16x8*)(op + g8 * 8) = o;
    }
}

// ---------------------------------------------------------------------------
extern "C" void kernel_launch(void* const* d_in, const int* in_sizes, int n_in,
                              void* d_out, int out_size, void* d_ws, size_t ws_size,
                              hipStream_t stream)
{
    const float* x       = (const float*)d_in[0];
    const float* rpb     = (const float*)d_in[1];
    const float* w_qkv   = (const float*)d_in[2];
    const float* w_depth = (const float*)d_in[3];
    const float* w_pre   = (const float*)d_in[4];
    const float* w_out   = (const float*)d_in[5];
    const float* w_gate  = (const float*)d_in[6];
    float* out = (float*)d_out;

    // workspace layout (176.7 MB), aliased by lifetime:
    //   [0, 442368)              w_bf (4 matrices bf16)
    //   [524288, 25690112)       gate_t bf16 [NPX][192]
    //   regionA [25690112, 101187584): t px-major bf16 [NPX][576] (75.5MB);
    //       later att_t @25690112, y_t @50855936 (each [NPX][192], 25.2MB)
    //   regionB [101187584, 176685056): x_t @101187584 ([NPX][192], dead
    //       before dwconv writes); later qkv px-major [NPX][576] (75.5MB)
    char* wsb = (char*)d_ws;
    ushort_t* wbf      = (ushort_t*)wsb;
    ushort_t* w_qkv_b  = wbf;
    ushort_t* w_gate_b = wbf + 110592;
    ushort_t* w_pre_b  = wbf + 147456;
    ushort_t* w_out_b  = wbf + 184320;
    ushort_t* gate_t   = (ushort_t*)(wsb + 524288u);
    ushort_t* buf_t    = (ushort_t*)(wsb + 25690112u);
    ushort_t* att_t    = (ushort_t*)(wsb + 25690112u);
    ushort_t* y_t      = (ushort_t*)(wsb + 50855936u);
    ushort_t* buf_qkv  = (ushort_t*)(wsb + 101187584u);
    ushort_t* x_t      = (ushort_t*)(wsb + 101187584u);

    dim3 blk(256);

    prep_w_kernel<<<dim3(216), blk, 0, stream>>>(w_qkv, w_gate, w_pre, w_out, wbf);
    transpose_x_kernel<<<dim3(NPX / 64), blk, 0, stream>>>(x, x_t);
    // gate_t = silu(x_t @ w_gate)             px-major bf16
    conv_mfma_kernel<1, 0, 3><<<dim3(768), blk, 0, stream>>>(
        x_t, w_gate_b, gate_t, nullptr, C);
    // t = x_t @ w_qkv (q-rows pre-scaled)     px-major bf16 [px][576]
    conv_mfma_kernel<0, 0, 9><<<dim3(2304), blk, 0, stream>>>(
        x_t, w_qkv_b, buf_t, nullptr, C3);
    // qkv = depthwise3x3(t)                   px-major bf16 [px][576]
    dwconv3x3_px_kernel<<<dim3(NPX / 128, 9), blk, 0, stream>>>(
        buf_t, w_depth, buf_qkv);
    // att_t = attention(qkv, rpb)             px-major bf16
    attention_mfma_kernel<<<dim3(H, HEADS, BATCH), blk, 0, stream>>>(
        buf_qkv, rpb, att_t);
    // y_t = (att_t @ w_pre) * gate_t          px-major bf16
    conv_mfma_kernel<2, 0, 3><<<dim3(768), blk, 0, stream>>>(
        att_t, w_pre_b, y_t, gate_t, C);
    // out = y_t @ w_out                       ch-major f32
    conv_mfma_kernel<0, 1, 3><<<dim3(768), blk, 0, stream>>>(
        y_t, w_out_b, out, nullptr, C);
}

// Round 8
// 351.279 us; speedup vs baseline: 2.8907x; 1.0632x over previous
//
#include <hip/hip_runtime.h>
#include <hip/hip_bf16.h>
#include <math.h>

#define BATCH 2
#define C 192
#define H 128
#define W 256
#define HEADS 6
#define HD 32
#define HW (H * W)      // 32768
#define C3 (3 * C)      // 576
#define NPX (BATCH * HW)  // 65536

typedef unsigned short ushort_t;
using bf16x8 = __attribute__((ext_vector_type(8))) short;
using f32x4  = __attribute__((ext_vector_type(4))) float;

static __device__ __forceinline__ float bfbits2f(ushort_t u) {
    return __uint_as_float(((unsigned)u) << 16);
}
static __device__ __forceinline__ ushort_t f2bfbits(float f) {
    __hip_bfloat16 h = __float2bfloat16(f);
    return *reinterpret_cast<ushort_t*>(&h);
}

// ---------------------------------------------------------------------------
// prep_w: fp32 -> bf16 weights; q-rows of w_qkv pre-scaled by 32^-0.5.
// ---------------------------------------------------------------------------
__global__ __launch_bounds__(256) void prep_w_kernel(
    const float* __restrict__ wq, const float* __restrict__ wg,
    const float* __restrict__ wp, const float* __restrict__ wo,
    ushort_t* __restrict__ dst)
{
    const int i = blockIdx.x * 256 + threadIdx.x;   // float4 index, < 55296
    const float* src; int off, base;
    if (i < 27648)      { src = wq; off = i;         base = 0; }
    else if (i < 36864) { src = wg; off = i - 27648; base = 110592; }
    else if (i < 46080) { src = wp; off = i - 36864; base = 147456; }
    else                { src = wo; off = i - 46080; base = 184320; }
    float4 v = ((const float4*)src)[off];
    if (i < 9216) {   // w_qkv rows 0..191 (the q projection)
        const float sc = 0.17677669529663687f;
        v.x *= sc; v.y *= sc; v.z *= sc; v.w *= sc;
    }
    ushort4 o;
    o.x = f2bfbits(v.x); o.y = f2bfbits(v.y);
    o.z = f2bfbits(v.z); o.w = f2bfbits(v.w);
    *(ushort4*)(dst + base + off * 4) = o;
}

// ---------------------------------------------------------------------------
// transpose_x: x [B][192][HW] f32 -> x_t [B*HW][192] bf16 (pixel-major).
// ---------------------------------------------------------------------------
__global__ __launch_bounds__(256) void transpose_x_kernel(
    const float* __restrict__ x, ushort_t* __restrict__ xt)
{
    __shared__ uint Xs[64 * 97];   // 24.8 KB
    const int p0 = blockIdx.x * 64;
    const int b  = p0 >> 15, hw0 = p0 & (HW - 1);
    const int t  = threadIdx.x;

    {
        const int px = t & 63, g = t >> 6;
        const float* xb = x + (size_t)b * C * HW + hw0 + px;
#pragma unroll
        for (int i = 0; i < 24; ++i) {
            const int cp = g + i * 4;   // channel pair 0..95
            const float v0 = xb[(size_t)(2 * cp) * HW];
            const float v1 = xb[(size_t)(2 * cp + 1) * HW];
            Xs[px * 97 + cp] = (uint)f2bfbits(v0) | ((uint)f2bfbits(v1) << 16);
        }
    }
    __syncthreads();
    {
        const int px = t >> 2, grp = t & 3;
        uint* dst = (uint*)(xt + (size_t)(p0 + px) * C) + grp * 24;
        const uint* s = &Xs[px * 97 + grp * 24];
#pragma unroll
        for (int i = 0; i < 6; ++i) {
            uint4 u;
            u.x = s[i * 4 + 0]; u.y = s[i * 4 + 1];
            u.z = s[i * 4 + 2]; u.w = s[i * 4 + 3];
            *(uint4*)(dst + i * 4) = u;
        }
    }
}

// ---------------------------------------------------------------------------
// MFMA conv1x1 GEMM v2. Block: 4 waves; tile M=64(ch) x N=512(px), K=192.
// - Weights tile staged ONCE in LDS (padded stride 200 ushorts -> 100 dwords:
//   l16 lanes land 2/bank = conflict-free); kills the A-gathers and the
//   4-wave redundancy of R7.
// - Wave tile 64x128 (ct=8): 32 MFMA per 8 B-gathers (2x R7 intensity).
// - Manual 1-deep prefetch of the next K-step's B frags over the MFMA block.
// XCD-swizzled 1-D grid: lin = xcd + 8*(m + MT*pin), pin 0..15 (NPX/512=128
// px tiles = 8 xcd * 16), so all MT m-blocks of a px-tile share one XCD L2.
// OUTKIND 0: px-major bf16 [px][ostride]; 1: ch-major f32 (final output).
// ---------------------------------------------------------------------------
template <int MODE, int OUTKIND, int MT>
__global__ __launch_bounds__(256) void conv_mfma_kernel(
    const ushort_t* __restrict__ in_t, const ushort_t* __restrict__ w_bf,
    void* __restrict__ outp, const ushort_t* __restrict__ gate, int ostride)
{
    const int lin = blockIdx.x;
    const int xcd = lin & 7;
    const int jj  = lin >> 3;
    const int pin = jj / MT;            // 0..15
    const int m   = jj - pin * MT;      // 0..MT-1
    const int m0  = m * 64;
    const int p0  = (xcd * 16 + pin) * 512;

    const int t  = threadIdx.x;
    const int wv = t >> 6, lane = t & 63, quad = lane >> 4, l16 = lane & 15;

    // ---- stage A (weights m0..m0+63 x 192) into LDS, padded to 200 ----
    __shared__ ushort_t As[64 * 200];   // 25.6 KB
    {
        const int row = t >> 2, cg = (t & 3) * 48;
        const ushort_t* src = w_bf + (size_t)(m0 + row) * C + cg;
        ushort_t* dst = &As[row * 200 + cg];
#pragma unroll
        for (int i = 0; i < 6; ++i)
            *(bf16x8*)(dst + i * 8) = *(const bf16x8*)(src + i * 8);
    }
    __syncthreads();

    f32x4 acc[4][8];
#pragma unroll
    for (int rt = 0; rt < 4; ++rt)
#pragma unroll
        for (int ct = 0; ct < 8; ++ct) acc[rt][ct] = f32x4{0.f, 0.f, 0.f, 0.f};

    const ushort_t* bp = in_t + (size_t)(p0 + wv * 128 + l16) * C + quad * 8;

    bf16x8 bF[8], bFn[8];
#pragma unroll
    for (int ct = 0; ct < 8; ++ct)
        bF[ct] = *(const bf16x8*)(bp + (size_t)(ct * 16) * C);

#pragma unroll
    for (int ks = 0; ks < 6; ++ks) {
        if (ks < 5) {
#pragma unroll
            for (int ct = 0; ct < 8; ++ct)
                bFn[ct] = *(const bf16x8*)(bp + (size_t)(ct * 16) * C +
                                           (ks + 1) * 32);
        }
        bf16x8 aF[4];
#pragma unroll
        for (int rt = 0; rt < 4; ++rt)
            aF[rt] = *(const bf16x8*)&As[(rt * 16 + l16) * 200 + quad * 8 + ks * 32];
#pragma unroll
        for (int rt = 0; rt < 4; ++rt)
#pragma unroll
            for (int ct = 0; ct < 8; ++ct)
                acc[rt][ct] = __builtin_amdgcn_mfma_f32_16x16x32_bf16(
                    aF[rt], bF[ct], acc[rt][ct], 0, 0, 0);
#pragma unroll
        for (int ct = 0; ct < 8; ++ct) bF[ct] = bFn[ct];
    }

    // ---- epilogue ----
#pragma unroll
    for (int rt = 0; rt < 4; ++rt)
#pragma unroll
        for (int ct = 0; ct < 8; ++ct) {
            f32x4 v = acc[rt][ct];
            if (MODE == 1) {
#pragma unroll
                for (int r = 0; r < 4; ++r)
                    v[r] = v[r] / (1.f + __expf(-v[r]));
            }
            acc[rt][ct] = v;
        }

    if constexpr (OUTKIND == 0) {
        ushort_t* ob = (ushort_t*)outp;
#pragma unroll
        for (int rt = 0; rt < 4; ++rt)
#pragma unroll
            for (int ct = 0; ct < 8; ++ct) {
                const int px = p0 + wv * 128 + ct * 16 + l16;
                const int ch = m0 + rt * 16 + quad * 4;
                f32x4 v = acc[rt][ct];
                if (MODE == 2) {
                    const ushort4 g = *(const ushort4*)(gate + (size_t)px * C + ch);
                    v[0] *= bfbits2f(g.x); v[1] *= bfbits2f(g.y);
                    v[2] *= bfbits2f(g.z); v[3] *= bfbits2f(g.w);
                }
                ushort4 o;
                o.x = f2bfbits(v[0]); o.y = f2bfbits(v[1]);
                o.z = f2bfbits(v[2]); o.w = f2bfbits(v[3]);
                *(ushort4*)(ob + (size_t)px * ostride + ch) = o;
            }
    } else {
        // channel-major f32 [B][192][HW] (final output)
        const int bb = p0 >> 15;
        const int hwb = (p0 & (HW - 1)) + wv * 128;
        float* ob = (float*)outp + ((size_t)bb * C + m0) * HW + hwb;
#pragma unroll
        for (int rt = 0; rt < 4; ++rt)
#pragma unroll
            for (int ct = 0; ct < 8; ++ct) {
                const f32x4 v = acc[rt][ct];
#pragma unroll
                for (int r = 0; r < 4; ++r)
                    ob[(size_t)(rt * 16 + quad * 4 + r) * HW + ct * 16 + l16] = v[r];
            }
    }
}

// ---------------------------------------------------------------------------
// depthwise 3x3, pixel-major (unchanged from R7).
// ---------------------------------------------------------------------------
__global__ __launch_bounds__(256) void dwconv3x3_px_kernel(
    const ushort_t* __restrict__ tin, const float* __restrict__ wd,
    ushort_t* __restrict__ out)
{
    __shared__ float wloc[576];
    const int cb  = blockIdx.y;
    const int tid = threadIdx.x;
    if (tid < 144)
        *(float4*)&wloc[tid * 4] = *(const float4*)(wd + cb * 576 + tid * 4);
    __syncthreads();

    const int chloc = (tid & 7) * 8;
    const int px = blockIdx.x * 128 + (tid >> 3) * 4;
    const int x0 = px & (W - 1);
    const int y  = (px >> 8) & (H - 1);

    const ushort_t* tb = tin + (size_t)px * C3 + cb * 64 + chloc;

    float acc[4][8];
#pragma unroll
    for (int i = 0; i < 4; ++i)
#pragma unroll
        for (int k = 0; k < 8; ++k) acc[i][k] = 0.f;

#pragma unroll
    for (int dy = -1; dy <= 1; ++dy) {
        const int yy = y + dy;
        if (yy < 0 || yy >= H) continue;
        const ushort_t* rp = tb + (ptrdiff_t)dy * W * C3;

        float f[6][8];
#pragma unroll
        for (int d = 0; d < 6; ++d) {
            const int xx = x0 + d - 1;
            if (xx < 0 || xx >= W) {
#pragma unroll
                for (int k = 0; k < 8; ++k) f[d][k] = 0.f;
            } else {
                const bf16x8 v = *(const bf16x8*)(rp + (ptrdiff_t)(d - 1) * C3);
#pragma unroll
                for (int k = 0; k < 8; ++k) f[d][k] = bfbits2f((ushort_t)v[k]);
            }
        }
#pragma unroll
        for (int k = 0; k < 8; ++k) {
            const float* wk = &wloc[(chloc + k) * 9 + (dy + 1) * 3];
            const float w0 = wk[0], w1 = wk[1], w2 = wk[2];
#pragma unroll
            for (int i = 0; i < 4; ++i)
                acc[i][k] += f[i][k] * w0 + f[i + 1][k] * w1 + f[i + 2][k] * w2;
        }
    }

    ushort_t* ob = out + (size_t)px * C3 + cb * 64 + chloc;
#pragma unroll
    for (int i = 0; i < 4; ++i) {
        bf16x8 o;
#pragma unroll
        for (int k = 0; k < 8; ++k) o[k] = (short)f2bfbits(acc[i][k]);
        *(bf16x8*)(ob + (size_t)i * C3) = o;
    }
}

// ---------------------------------------------------------------------------
// MFMA attention, single pass (unchanged from R7).
// ---------------------------------------------------------------------------
__global__ __launch_bounds__(256) void attention_mfma_kernel(
    const ushort_t* __restrict__ qkv, const float* __restrict__ rpb,
    ushort_t* __restrict__ att)
{
    const int y    = blockIdx.x;
    const int head = blockIdx.y;
    const int b    = blockIdx.z;
    const int t    = threadIdx.x;
    const int wv   = t >> 6;
    const int lane = t & 63;
    const int quad = lane >> 4;
    const int l16  = lane & 15;

    __shared__ __align__(16) char smem[61952];
    ushort_t* Ks  = (ushort_t*)smem;              // [256][40]
    ushort_t* Vt  = (ushort_t*)(smem + 20480);    // [32][264]
    ushort_t* Qs  = (ushort_t*)(smem + 37376);    // [256][40] -> Pbuf
    ushort_t* rb4 = (ushort_t*)(smem + 57856);    // [4][512]
    float*    Ol  = (float*)smem;                 // [32][257]

    const ushort_t* rowp = qkv + ((size_t)b * HW + (size_t)y * W + t) * C3 +
                           head * HD;
    bf16x8 vfr[4];
#pragma unroll
    for (int g = 0; g < 4; ++g) {
        *(bf16x8*)&Qs[t * 40 + g * 8] = *(const bf16x8*)(rowp + g * 8);
        *(bf16x8*)&Ks[t * 40 + g * 8] = *(const bf16x8*)(rowp + C + g * 8);
        vfr[g] = *(const bf16x8*)(rowp + 2 * C + g * 8);
    }
#pragma unroll
    for (int g = 0; g < 4; ++g)
#pragma unroll
        for (int k = 0; k < 8; ++k)
            Vt[(g * 8 + k) * 264 + t] = (ushort_t)vfr[g][k];

#pragma unroll
    for (int s = 0; s < 4; ++s) {
        const int k1 = t, k2 = 256 + t;
        const float v1 = (k1 + s < 511) ? rpb[(k1 + s) * HEADS + head] : 0.f;
        const float v2 = (k2 + s < 511) ? rpb[(k2 + s) * HEADS + head] : 0.f;
        rb4[s * 512 + k1] = f2bfbits(v1);
        rb4[s * 512 + k2] = f2bfbits(v2);
    }
    __syncthreads();

    bf16x8 aQ[4];
#pragma unroll
    for (int rt = 0; rt < 4; ++rt) {
        const int row = wv * 64 + rt * 16 + l16;
        aQ[rt] = *(const bf16x8*)&Qs[row * 40 + quad * 8];
    }
    __syncthreads();
    ushort_t* Pb = Qs + wv * 2560;

    float l_acc[16];
#pragma unroll
    for (int i = 0; i < 16; ++i) l_acc[i] = 0.f;
    f32x4 o_acc[4][2];
#pragma unroll
    for (int rt = 0; rt < 4; ++rt)
#pragma unroll
        for (int ct = 0; ct < 2; ++ct)
            o_acc[rt][ct] = f32x4{0.f, 0.f, 0.f, 0.f};

    for (int c2 = 0; c2 < 8; ++c2) {
#pragma unroll
        for (int half = 0; half < 2; ++half) {
            const int n = c2 * 2 + half;
            const bf16x8 bK = *(const bf16x8*)&Ks[(n * 16 + l16) * 40 + quad * 8];
#pragma unroll
            for (int rt = 0; rt < 4; ++rt) {
                const int base = wv * 64 + rt * 16 + quad * 4 - (n * 16 + l16) + 255;
                const int r0 = base & 3;
                const uint2 raw = *(const uint2*)(rb4 + r0 * 512 + (base - r0));
                f32x4 s;
                s[0] = __uint_as_float(raw.x << 16);
                s[1] = __uint_as_float(raw.x & 0xffff0000u);
                s[2] = __uint_as_float(raw.y << 16);
                s[3] = __uint_as_float(raw.y & 0xffff0000u);
                s = __builtin_amdgcn_mfma_f32_16x16x32_bf16(aQ[rt], bK, s, 0, 0, 0);
#pragma unroll
                for (int reg = 0; reg < 4; ++reg) {
                    const float p = __expf(s[reg]);
                    l_acc[rt * 4 + reg] += p;
                    Pb[(rt * 16 + quad * 4 + reg) * 40 + half * 16 + l16] =
                        f2bfbits(p);
                }
            }
        }
#pragma unroll
        for (int rt = 0; rt < 4; ++rt) {
            const bf16x8 aP = *(const bf16x8*)&Pb[(rt * 16 + l16) * 40 + quad * 8];
#pragma unroll
            for (int ct = 0; ct < 2; ++ct) {
                const bf16x8 bV = *(const bf16x8*)
                    &Vt[(ct * 16 + l16) * 264 + c2 * 32 + quad * 8];
                o_acc[rt][ct] = __builtin_amdgcn_mfma_f32_16x16x32_bf16(
                    aP, bV, o_acc[rt][ct], 0, 0, 0);
            }
        }
    }

#pragma unroll
    for (int i = 0; i < 16; ++i) {
        float v = l_acc[i];
        v += __shfl_xor(v, 1);
        v += __shfl_xor(v, 2);
        v += __shfl_xor(v, 4);
        v += __shfl_xor(v, 8);
        l_acc[i] = 1.f / v;
    }

    __syncthreads();
#pragma unroll
    for (int rt = 0; rt < 4; ++rt) {
        const int i = wv * 64 + rt * 16 + quad * 4;
#pragma unroll
        for (int ct = 0; ct < 2; ++ct) {
            const int c = ct * 16 + l16;
#pragma unroll
            for (int reg = 0; reg < 4; ++reg)
                Ol[c * 257 + i + reg] = o_acc[rt][ct][reg] * l_acc[rt * 4 + reg];
        }
    }
    __syncthreads();

    ushort_t* op = att + ((size_t)b * HW + (size_t)y * W + t) * C + head * HD;
#pragma unroll
    for (int g8 = 0; g8 < 4; ++g8) {
        bf16x8 o;
#pragma unroll
        for (int k = 0; k < 8; ++k)
            o[k] = (short)f2bfbits(Ol[(g8 * 8 + k) * 257 + t]);
        *(bf16x8*)(op + g8 * 8) = o;
    }
}

// ---------------------------------------------------------------------------
extern "C" void kernel_launch(void* const* d_in, const int* in_sizes, int n_in,
                              void* d_out, int out_size, void* d_ws, size_t ws_size,
                              hipStream_t stream)
{
    const float* x       = (const float*)d_in[0];
    const float* rpb     = (const float*)d_in[1];
    const float* w_qkv   = (const float*)d_in[2];
    const float* w_depth = (const float*)d_in[3];
    const float* w_pre   = (const float*)d_in[4];
    const float* w_out   = (const float*)d_in[5];
    const float* w_gate  = (const float*)d_in[6];
    float* out = (float*)d_out;

    // workspace layout (176.7 MB), aliased by lifetime (as R7):
    char* wsb = (char*)d_ws;
    ushort_t* wbf      = (ushort_t*)wsb;
    ushort_t* w_qkv_b  = wbf;
    ushort_t* w_gate_b = wbf + 110592;
    ushort_t* w_pre_b  = wbf + 147456;
    ushort_t* w_out_b  = wbf + 184320;
    ushort_t* gate_t   = (ushort_t*)(wsb + 524288u);
    ushort_t* buf_t    = (ushort_t*)(wsb + 25690112u);
    ushort_t* att_t    = (ushort_t*)(wsb + 25690112u);
    ushort_t* y_t      = (ushort_t*)(wsb + 50855936u);
    ushort_t* buf_qkv  = (ushort_t*)(wsb + 101187584u);
    ushort_t* x_t      = (ushort_t*)(wsb + 101187584u);

    dim3 blk(256);

    prep_w_kernel<<<dim3(216), blk, 0, stream>>>(w_qkv, w_gate, w_pre, w_out, wbf);
    transpose_x_kernel<<<dim3(NPX / 64), blk, 0, stream>>>(x, x_t);
    // gate_t = silu(x_t @ w_gate)             px-major bf16
    conv_mfma_kernel<1, 0, 3><<<dim3(384), blk, 0, stream>>>(
        x_t, w_gate_b, gate_t, nullptr, C);
    // t = x_t @ w_qkv (q-rows pre-scaled)     px-major bf16 [px][576]
    conv_mfma_kernel<0, 0, 9><<<dim3(1152), blk, 0, stream>>>(
        x_t, w_qkv_b, buf_t, nullptr, C3);
    // qkv = depthwise3x3(t)                   px-major bf16 [px][576]
    dwconv3x3_px_kernel<<<dim3(NPX / 128, 9), blk, 0, stream>>>(
        buf_t, w_depth, buf_qkv);
    // att_t = attention(qkv, rpb)             px-major bf16
    attention_mfma_kernel<<<dim3(H, HEADS, BATCH), blk, 0, stream>>>(
        buf_qkv, rpb, att_t);
    // y_t = (att_t @ w_pre) * gate_t          px-major bf16
    conv_mfma_kernel<2, 0, 3><<<dim3(384), blk, 0, stream>>>(
        att_t, w_pre_b, y_t, gate_t, C);
    // out = y_t @ w_out                       ch-major f32
    conv_mfma_kernel<0, 1, 3><<<dim3(384), blk, 0, stream>>>(
        y_t, w_out_b, out, nullptr, C);
}